// Round 1
// baseline (2600.756 us; speedup 1.0000x reference)
//
#include <hip/hip_runtime.h>
#include <cmath>

#define BM 64
#define BN 64
#define BK 16

enum { EPI_BIAS = 0, EPI_TANH = 1, EPI_SILU = 2, EPI_SCALE = 3, EPI_SIGMUL = 4 };

// C[m,n] = epi( sum_k A[m,k] * B[n,k] + bias[n] )   (A: MxK row-major, B: NxK row-major)
// CONCAT=true: A is the virtual [r_prev | r_t] matrix built from R (4096x1024), K must be 2048.
template <int EPI, bool CONCAT>
__global__ __launch_bounds__(256) void gemm_nt(const float* __restrict__ A,
                                               const float* __restrict__ B,
                                               const float* __restrict__ bias,
                                               const float* __restrict__ aux,
                                               float* __restrict__ C,
                                               int M, int N, int K, float scale) {
  __shared__ __align__(16) float As[BK][BM + 4];
  __shared__ __align__(16) float Bs[BK][BN + 4];
  const int tid = threadIdx.x;
  const int tx = tid & 15, ty = tid >> 4;
  const int bm = blockIdx.y * BM, bn = blockIdx.x * BN;
  const int r = tid >> 2, kq = (tid & 3) * 4;  // staging: row r (0..63), 4 consecutive k
  float acc[4][4] = {};

  for (int k0 = 0; k0 < K; k0 += BK) {
    float4 av, bv;
    if (!CONCAT) {
      av = *reinterpret_cast<const float4*>(&A[(size_t)(bm + r) * K + (k0 + kq)]);
    } else {
      const int m = bm + r, k = k0 + kq;
      if (k < 1024) {
        if (m > 0)
          av = *reinterpret_cast<const float4*>(&A[(size_t)(m - 1) * 1024 + k]);
        else
          av = make_float4(0.f, 0.f, 0.f, 0.f);
      } else {
        av = *reinterpret_cast<const float4*>(&A[(size_t)m * 1024 + (k - 1024)]);
      }
    }
    bv = *reinterpret_cast<const float4*>(&B[(size_t)(bn + r) * K + (k0 + kq)]);
    As[kq + 0][r] = av.x; As[kq + 1][r] = av.y; As[kq + 2][r] = av.z; As[kq + 3][r] = av.w;
    Bs[kq + 0][r] = bv.x; Bs[kq + 1][r] = bv.y; Bs[kq + 2][r] = bv.z; Bs[kq + 3][r] = bv.w;
    __syncthreads();
#pragma unroll
    for (int kk = 0; kk < BK; ++kk) {
      const float4 a = *reinterpret_cast<const float4*>(&As[kk][ty * 4]);
      const float4 b = *reinterpret_cast<const float4*>(&Bs[kk][tx * 4]);
      acc[0][0] += a.x * b.x; acc[0][1] += a.x * b.y; acc[0][2] += a.x * b.z; acc[0][3] += a.x * b.w;
      acc[1][0] += a.y * b.x; acc[1][1] += a.y * b.y; acc[1][2] += a.y * b.z; acc[1][3] += a.y * b.w;
      acc[2][0] += a.z * b.x; acc[2][1] += a.z * b.y; acc[2][2] += a.z * b.z; acc[2][3] += a.z * b.w;
      acc[3][0] += a.w * b.x; acc[3][1] += a.w * b.y; acc[3][2] += a.w * b.z; acc[3][3] += a.w * b.w;
    }
    __syncthreads();
  }

#pragma unroll
  for (int i = 0; i < 4; ++i) {
    const int m = bm + ty * 4 + i;
    float4 o;
#pragma unroll
    for (int j = 0; j < 4; ++j) {
      const int n = bn + tx * 4 + j;
      float v = acc[i][j];
      if (EPI == EPI_SCALE) {
        v *= scale;
      } else {
        if (bias) v += bias[n];
        if (EPI == EPI_TANH) v = tanhf(v);
        else if (EPI == EPI_SILU) v = v / (1.f + expf(-v));
        else if (EPI == EPI_SIGMUL) v = (1.f / (1.f + expf(-v))) * aux[(size_t)m * N + n];
      }
      (&o.x)[j] = v;
    }
    *reinterpret_cast<float4*>(&C[(size_t)m * N + bn + tx * 4]) = o;
  }
}

// REMA = alpha * r_t + (1-alpha) * delta * r_prev   (alpha/delta already tanh'd)
__global__ __launch_bounds__(256) void ema_combine(const float* __restrict__ R,
                                                   const float* __restrict__ alpha,
                                                   const float* __restrict__ delta,
                                                   float* __restrict__ REMA) {
  const size_t idx = (size_t)blockIdx.x * 256 + threadIdx.x;  // float4 index, 1M total
  const int m = (int)(idx >> 8);                              // 256 float4 per 1024-col row
  const float4 rt = reinterpret_cast<const float4*>(R)[idx];
  float4 rp = make_float4(0.f, 0.f, 0.f, 0.f);
  if (m > 0) rp = reinterpret_cast<const float4*>(R)[idx - 256];
  const float4 a = reinterpret_cast<const float4*>(alpha)[idx];
  const float4 d = reinterpret_cast<const float4*>(delta)[idx];
  float4 o;
  o.x = a.x * rt.x + (1.f - a.x) * d.x * rp.x;
  o.y = a.y * rt.y + (1.f - a.y) * d.y * rp.y;
  o.z = a.z * rt.z + (1.f - a.z) * d.z * rp.z;
  o.w = a.w * rt.w + (1.f - a.w) * d.w * rp.w;
  reinterpret_cast<float4*>(REMA)[idx] = o;
}

__device__ inline float waveMax(float v) {
#pragma unroll
  for (int o = 32; o; o >>= 1) v = fmaxf(v, __shfl_down(v, o));
  return v;
}
__device__ inline float waveSum(float v) {
#pragma unroll
  for (int o = 32; o; o >>= 1) v += __shfl_down(v, o);
  return v;
}

// in-place softmax over rows of S (cols = 4096), one block (256 thr) per row
__global__ __launch_bounds__(256) void softmax_rows(float* __restrict__ S, int cols) {
  float* p = S + (size_t)blockIdx.x * cols;
  const int tid = threadIdx.x;
  float v[16];
#pragma unroll
  for (int j = 0; j < 4; ++j) {
    const float4 t = *reinterpret_cast<const float4*>(&p[tid * 4 + 1024 * j]);
    v[4 * j + 0] = t.x; v[4 * j + 1] = t.y; v[4 * j + 2] = t.z; v[4 * j + 3] = t.w;
  }
  float mx = -INFINITY;
#pragma unroll
  for (int j = 0; j < 16; ++j) mx = fmaxf(mx, v[j]);
  __shared__ float red[4];
  float wm = waveMax(mx);
  if ((tid & 63) == 0) red[tid >> 6] = wm;
  __syncthreads();
  mx = fmaxf(fmaxf(red[0], red[1]), fmaxf(red[2], red[3]));
  __syncthreads();
  float sum = 0.f;
#pragma unroll
  for (int j = 0; j < 16; ++j) {
    v[j] = expf(v[j] - mx);
    sum += v[j];
  }
  float ws_ = waveSum(sum);
  if ((tid & 63) == 0) red[tid >> 6] = ws_;
  __syncthreads();
  sum = red[0] + red[1] + red[2] + red[3];
  const float inv = 1.f / sum;
#pragma unroll
  for (int j = 0; j < 4; ++j) {
    float4 t;
    t.x = v[4 * j + 0] * inv; t.y = v[4 * j + 1] * inv;
    t.z = v[4 * j + 2] * inv; t.w = v[4 * j + 3] * inv;
    *reinterpret_cast<float4*>(&p[tid * 4 + 1024 * j]) = t;
  }
}

// VT[n,k] = V[k,n]; V: 4096x1024
__global__ __launch_bounds__(256) void transpose_kern(const float* __restrict__ V,
                                                      float* __restrict__ VT) {
  __shared__ float t[32][33];
  const int bx = blockIdx.x * 32;  // n
  const int by = blockIdx.y * 32;  // k
  for (int i = threadIdx.y; i < 32; i += 8)
    t[i][threadIdx.x] = V[(size_t)(by + i) * 1024 + bx + threadIdx.x];
  __syncthreads();
  for (int i = threadIdx.y; i < 32; i += 8)
    VT[(size_t)(bx + i) * 4096 + by + threadIdx.x] = t[threadIdx.x][i];
}

// iv[m] = tanh( dot(REMA[m,:], Wi) + bi )
__global__ void rowdot_i(const float* __restrict__ REMA, const float* __restrict__ Wi,
                         const float* __restrict__ bi, float* __restrict__ iv) {
  const int m = blockIdx.x, l = threadIdx.x;
  float s = 0.f;
#pragma unroll
  for (int j = 0; j < 16; ++j) s += REMA[(size_t)m * 1024 + l + 64 * j] * Wi[l + 64 * j];
#pragma unroll
  for (int o = 32; o; o >>= 1) s += __shfl_down(s, o);
  if (l == 0) iv[m] = tanhf(s + bi[0]);
}

// out[m] = sigmoid( dot( i*tanh(REMAp+ZEMAf) + (1-i)*REMAp , W_final ) )
__global__ void final_kern(const float* __restrict__ REMAp, const float* __restrict__ ZEMAf,
                           const float* __restrict__ iv, const float* __restrict__ Wfin,
                           float* __restrict__ out) {
  const int m = blockIdx.x, l = threadIdx.x;
  const float im = iv[m];
  float s = 0.f;
#pragma unroll
  for (int j = 0; j < 16; ++j) {
    const int n = l + 64 * j;
    const float rp = REMAp[(size_t)m * 1024 + n];
    const float zf = im * tanhf(rp + ZEMAf[(size_t)m * 1024 + n]) + (1.f - im) * rp;
    s += zf * Wfin[n];
  }
#pragma unroll
  for (int o = 32; o; o >>= 1) s += __shfl_down(s, o);
  if (l == 0) out[m] = 1.f / (1.f + expf(-s));
}

extern "C" void kernel_launch(void* const* d_in, const int* in_sizes, int n_in,
                              void* d_out, int out_size, void* d_ws, size_t ws_size,
                              hipStream_t stream) {
  const float* R       = (const float*)d_in[0];
  const float* W_alpha = (const float*)d_in[1];  const float* b_alpha = (const float*)d_in[2];
  const float* W_delta = (const float*)d_in[3];  const float* b_delta = (const float*)d_in[4];
  const float* W_q     = (const float*)d_in[5];  const float* b_q     = (const float*)d_in[6];
  const float* W_k     = (const float*)d_in[7];  const float* b_k     = (const float*)d_in[8];
  const float* W_v     = (const float*)d_in[9];  const float* b_v     = (const float*)d_in[10];
  const float* W_z     = (const float*)d_in[11]; const float* b_z     = (const float*)d_in[12];
  const float* W_f     = (const float*)d_in[13]; const float* b_f     = (const float*)d_in[14];
  const float* W_EMA   = (const float*)d_in[15]; const float* b_EMA   = (const float*)d_in[16];
  const float* W_z_at  = (const float*)d_in[17]; const float* b_z_at  = (const float*)d_in[18];
  const float* W_i     = (const float*)d_in[19]; const float* b_i     = (const float*)d_in[20];
  const float* W_final = (const float*)d_in[21];
  float* out = (float*)d_out;
  float* ws  = (float*)d_ws;

  const size_t SL = 4096ull * 1024ull;  // one 4096x1024 fp32 slab (16 MB)
  float* REMA = ws + 0 * SL;   // live to the end
  float* s1   = ws + 1 * SL;   // alphaL -> Z -> Schunk(1024x4096)
  float* s2   = ws + 2 * SL;   // deltaL -> Q
  float* s3   = ws + 3 * SL;   // K -> ZEMAf
  float* s4   = ws + 4 * SL;   // V -> REMAp
  float* s5   = ws + 5 * SL;   // VT (1024x4096)
  float* s6   = ws + 6 * SL;   // Z_at / Z_at_p
  float* iv   = ws + 7 * SL;   // 4096 floats
  // peak ws use: 7*16MB + 16KB = ~112 MB

  const dim3 blk(256);
  // alpha / delta (K=2048, virtual concat A)
  gemm_nt<EPI_TANH, true><<<dim3(16, 64), blk, 0, stream>>>(R, W_alpha, b_alpha, nullptr, s1, 4096, 1024, 2048, 1.f);
  gemm_nt<EPI_TANH, true><<<dim3(16, 64), blk, 0, stream>>>(R, W_delta, b_delta, nullptr, s2, 4096, 1024, 2048, 1.f);
  ema_combine<<<4096, 256, 0, stream>>>(R, s1, s2, REMA);
  // Z = silu(REMA @ Wz^T + bz)
  gemm_nt<EPI_SILU, false><<<dim3(16, 64), blk, 0, stream>>>(REMA, W_z, b_z, nullptr, s1, 4096, 1024, 1024, 1.f);
  // Q,K,V
  gemm_nt<EPI_BIAS, false><<<dim3(16, 64), blk, 0, stream>>>(s1, W_q, b_q, nullptr, s2, 4096, 1024, 1024, 1.f);
  gemm_nt<EPI_BIAS, false><<<dim3(16, 64), blk, 0, stream>>>(s1, W_k, b_k, nullptr, s3, 4096, 1024, 1024, 1.f);
  gemm_nt<EPI_BIAS, false><<<dim3(16, 64), blk, 0, stream>>>(s1, W_v, b_v, nullptr, s4, 4096, 1024, 1024, 1.f);
  transpose_kern<<<dim3(32, 128), dim3(32, 8), 0, stream>>>(s4, s5);
  // attention, 4 chunks of 1024 query rows; scores scratch = s1
  for (int c = 0; c < 4; ++c) {
    gemm_nt<EPI_SCALE, false><<<dim3(64, 16), blk, 0, stream>>>(s2 + (size_t)c * 1024 * 1024, s3, nullptr, nullptr, s1, 1024, 4096, 1024, 0.03125f);
    softmax_rows<<<1024, 256, 0, stream>>>(s1, 4096);
    gemm_nt<EPI_BIAS, false><<<dim3(16, 16), blk, 0, stream>>>(s1, s5, nullptr, nullptr, s6 + (size_t)c * 1024 * 1024, 1024, 1024, 4096, 1.f);
  }
  // R_EMA_p (into s4; V is dead after transpose)
  gemm_nt<EPI_BIAS, false><<<dim3(16, 64), blk, 0, stream>>>(REMA, W_EMA, b_EMA, nullptr, s4, 4096, 1024, 1024, 1.f);
  // Z_at_p = sigmoid(REMAp @ Wf^T + bf) * Z_at   (in-place on s6)
  gemm_nt<EPI_SIGMUL, false><<<dim3(16, 64), blk, 0, stream>>>(s4, W_f, b_f, s6, s6, 4096, 1024, 1024, 1.f);
  // Z_EMA_f (into s3; K dead)
  gemm_nt<EPI_BIAS, false><<<dim3(16, 64), blk, 0, stream>>>(s6, W_z_at, b_z_at, nullptr, s3, 4096, 1024, 1024, 1.f);
  // i vector + fused final
  rowdot_i<<<4096, 64, 0, stream>>>(REMA, W_i, b_i, iv);
  final_kern<<<4096, 64, 0, stream>>>(s4, s3, iv, W_final, out);
}

// Round 2
// 557.265 us; speedup vs baseline: 4.6670x; 4.6670x over previous
//
#include <hip/hip_runtime.h>
#include <cstdint>
#include <cmath>

#define MB (1024ull * 1024ull)

typedef unsigned short u16;
typedef __attribute__((ext_vector_type(8))) short short8;
typedef __attribute__((ext_vector_type(4))) float f32x4;

enum { EPI_NONE = 0, EPI_TANH = 1, EPI_SILU = 2, EPI_SCALE = 3, EPI_SIGMUL = 4 };
enum { OUT_B16 = 1, OUT_F32 = 2, OUT_DUAL = 3 };

__device__ __forceinline__ u16 f2b(float f) {
  union { float f; uint32_t u; } v; v.f = f;
  uint32_t r = v.u + 0x7FFFu + ((v.u >> 16) & 1u);
  return (u16)(r >> 16);
}
__device__ __forceinline__ float b2f(u16 u) {
  union { uint32_t u; float f; } v; v.u = ((uint32_t)u) << 16;
  return v.f;
}

typedef __attribute__((address_space(3))) uint32_t lds_u32;
typedef const __attribute__((address_space(1))) uint32_t glb_u32;

__device__ __forceinline__ void gload16(const void* g, void* l) {
  __builtin_amdgcn_global_load_lds((glb_u32*)g, (lds_u32*)l, 16, 0, 0);
}

// ---------------- MFMA GEMM: C = epi(A @ B^T + bias) ----------------
// A: MxK bf16 row-major, B: NxK bf16 row-major. M,N mult of 128; K mult of 32.
template <int EPI, int OUT>
__global__ __launch_bounds__(256) void gemm_bt(const u16* __restrict__ A,
                                               const u16* __restrict__ B,
                                               const float* __restrict__ bias,
                                               const float* __restrict__ aux,
                                               float* __restrict__ Cf,
                                               u16* __restrict__ Cb,
                                               int M, int N, int K, float scale) {
  __shared__ u16 As[128 * 32];
  __shared__ u16 Bs[128 * 32];
  const int tid = threadIdx.x;
  const int wid = tid >> 6, lane = tid & 63;
  const int bm = blockIdx.y * 128, bn = blockIdx.x * 128;
  const int wm = wid >> 1, wn = wid & 1;

  // staging coords: thread t covers tile elements [t*8, t*8+8) (row-major [128][32])
  const int srow = tid >> 2;
  const int scol = (tid & 3) * 8;
  const u16* gA = A + (size_t)(bm + srow) * K + scol;
  const u16* gB = B + (size_t)(bn + srow) * K + scol;
  u16* ldsA = &As[wid * 512];  // wave-uniform base; HW adds lane*16B
  u16* ldsB = &Bs[wid * 512];

  f32x4 acc[4][4];
#pragma unroll
  for (int i = 0; i < 4; ++i)
#pragma unroll
    for (int j = 0; j < 4; ++j) acc[i][j] = (f32x4){0.f, 0.f, 0.f, 0.f};

  const int ar = lane & 15;
  const int ak = (lane >> 4) * 8;

  for (int k0 = 0; k0 < K; k0 += 32) {
    gload16(gA, ldsA);
    gload16(gA + (size_t)64 * K, ldsA + 2048);
    gload16(gB, ldsB);
    gload16(gB + (size_t)64 * K, ldsB + 2048);
    gA += 32; gB += 32;
    __syncthreads();
    short8 af[4], bf[4];
#pragma unroll
    for (int i = 0; i < 4; ++i)
      af[i] = *reinterpret_cast<const short8*>(&As[(wm * 64 + i * 16 + ar) * 32 + ak]);
#pragma unroll
    for (int j = 0; j < 4; ++j)
      bf[j] = *reinterpret_cast<const short8*>(&Bs[(wn * 64 + j * 16 + ar) * 32 + ak]);
#pragma unroll
    for (int i = 0; i < 4; ++i)
#pragma unroll
      for (int j = 0; j < 4; ++j)
        acc[i][j] = __builtin_amdgcn_mfma_f32_16x16x32_bf16(af[i], bf[j], acc[i][j], 0, 0, 0);
    __syncthreads();
  }

#pragma unroll
  for (int i = 0; i < 4; ++i) {
    const int rb = bm + wm * 64 + i * 16 + (lane >> 4) * 4;
#pragma unroll
    for (int j = 0; j < 4; ++j) {
      const int n = bn + wn * 64 + j * 16 + (lane & 15);
      const float bv = (EPI != EPI_SCALE && bias != nullptr) ? bias[n] : 0.f;
#pragma unroll
      for (int r = 0; r < 4; ++r) {
        const int m = rb + r;
        float v = acc[i][j][r];
        if (EPI == EPI_SCALE) v *= scale;
        else v += bv;
        if (EPI == EPI_TANH) v = tanhf(v);
        else if (EPI == EPI_SILU) v = v / (1.f + expf(-v));
        else if (EPI == EPI_SIGMUL) v = (1.f / (1.f + expf(-v))) * aux[(size_t)m * N + n];
        if (OUT & OUT_F32) Cf[(size_t)m * N + n] = v;
        if (OUT & OUT_B16) Cb[(size_t)m * N + n] = f2b(v);
      }
    }
  }
}

// ---------------- helpers ----------------
__global__ __launch_bounds__(256) void f2b_kern(const float* __restrict__ in,
                                                u16* __restrict__ out, int n4) {
  const int idx = blockIdx.x * 256 + threadIdx.x;
  if (idx < n4) {
    const float4 v = reinterpret_cast<const float4*>(in)[idx];
    ushort4 o; o.x = f2b(v.x); o.y = f2b(v.y); o.z = f2b(v.z); o.w = f2b(v.w);
    reinterpret_cast<ushort4*>(out)[idx] = o;
  }
}

// Rc[m][k] = k<1024 ? (m>0 ? R[m-1][k] : 0) : R[m][k-1024]   (bf16 out, [4096][2048])
__global__ __launch_bounds__(256) void concat_kern(const float* __restrict__ R,
                                                   u16* __restrict__ Rc) {
  const int idx = blockIdx.x * 256 + threadIdx.x;  // 2M groups of 4
  const int m = idx >> 9;
  const int c = (idx & 511) * 4;
  float4 v;
  if (c < 1024) {
    if (m > 0) v = *reinterpret_cast<const float4*>(&R[(size_t)(m - 1) * 1024 + c]);
    else v = make_float4(0.f, 0.f, 0.f, 0.f);
  } else {
    v = *reinterpret_cast<const float4*>(&R[(size_t)m * 1024 + (c - 1024)]);
  }
  ushort4 o; o.x = f2b(v.x); o.y = f2b(v.y); o.z = f2b(v.z); o.w = f2b(v.w);
  reinterpret_cast<ushort4*>(Rc)[idx] = o;
}

// REMA = alpha*r_t + (1-alpha)*delta*r_prev  -> bf16
__global__ __launch_bounds__(256) void ema_combine(const float* __restrict__ R,
                                                   const u16* __restrict__ a,
                                                   const u16* __restrict__ d,
                                                   u16* __restrict__ REMA) {
  const int idx = blockIdx.x * 256 + threadIdx.x;  // 1M groups of 4
  const int m = idx >> 8;
  const float4 rt = reinterpret_cast<const float4*>(R)[idx];
  float4 rp = make_float4(0.f, 0.f, 0.f, 0.f);
  if (m > 0) rp = reinterpret_cast<const float4*>(R)[idx - 256];
  const ushort4 a4 = reinterpret_cast<const ushort4*>(a)[idx];
  const ushort4 d4 = reinterpret_cast<const ushort4*>(d)[idx];
  ushort4 o;
  { float av = b2f(a4.x); o.x = f2b(av * rt.x + (1.f - av) * b2f(d4.x) * rp.x); }
  { float av = b2f(a4.y); o.y = f2b(av * rt.y + (1.f - av) * b2f(d4.y) * rp.y); }
  { float av = b2f(a4.z); o.z = f2b(av * rt.z + (1.f - av) * b2f(d4.z) * rp.z); }
  { float av = b2f(a4.w); o.w = f2b(av * rt.w + (1.f - av) * b2f(d4.w) * rp.w); }
  reinterpret_cast<ushort4*>(REMA)[idx] = o;
}

__device__ __forceinline__ float waveMax(float v) {
#pragma unroll
  for (int o = 32; o; o >>= 1) v = fmaxf(v, __shfl_down(v, o));
  return v;
}
__device__ __forceinline__ float waveSum(float v) {
#pragma unroll
  for (int o = 32; o; o >>= 1) v += __shfl_down(v, o);
  return v;
}

// in-place row softmax on bf16 scores, 4096 cols, one block per row
__global__ __launch_bounds__(256) void softmax_rows(u16* __restrict__ S) {
  u16* p = S + (size_t)blockIdx.x * 4096;
  const int tid = threadIdx.x;
  float v[16];
#pragma unroll
  for (int j = 0; j < 4; ++j) {
    const ushort4 t = *reinterpret_cast<const ushort4*>(&p[tid * 4 + 1024 * j]);
    v[4 * j + 0] = b2f(t.x); v[4 * j + 1] = b2f(t.y);
    v[4 * j + 2] = b2f(t.z); v[4 * j + 3] = b2f(t.w);
  }
  float mx = -INFINITY;
#pragma unroll
  for (int j = 0; j < 16; ++j) mx = fmaxf(mx, v[j]);
  __shared__ float red[4];
  const float wm = waveMax(mx);
  if ((tid & 63) == 0) red[tid >> 6] = wm;
  __syncthreads();
  mx = fmaxf(fmaxf(red[0], red[1]), fmaxf(red[2], red[3]));
  __syncthreads();
  float sum = 0.f;
#pragma unroll
  for (int j = 0; j < 16; ++j) { v[j] = expf(v[j] - mx); sum += v[j]; }
  const float ws_ = waveSum(sum);
  if ((tid & 63) == 0) red[tid >> 6] = ws_;
  __syncthreads();
  const float inv = 1.f / (red[0] + red[1] + red[2] + red[3]);
#pragma unroll
  for (int j = 0; j < 4; ++j) {
    ushort4 t;
    t.x = f2b(v[4 * j + 0] * inv); t.y = f2b(v[4 * j + 1] * inv);
    t.z = f2b(v[4 * j + 2] * inv); t.w = f2b(v[4 * j + 3] * inv);
    *reinterpret_cast<ushort4*>(&p[tid * 4 + 1024 * j]) = t;
  }
}

// Vt[n][k] = V[k][n]; V: [4096][1024] bf16 -> Vt: [1024][4096] bf16
__global__ __launch_bounds__(256) void transpose_b16(const u16* __restrict__ V,
                                                     u16* __restrict__ Vt) {
  __shared__ u16 t[64][72];
  const int bn = blockIdx.x * 64;  // col of V
  const int bk = blockIdx.y * 64;  // row of V
  const int tx = threadIdx.x & 15, ty = threadIdx.x >> 4;
#pragma unroll
  for (int i = 0; i < 64; i += 16) {
    const ushort4 v = *reinterpret_cast<const ushort4*>(&V[(size_t)(bk + ty + i) * 1024 + bn + tx * 4]);
    t[ty + i][tx * 4 + 0] = v.x; t[ty + i][tx * 4 + 1] = v.y;
    t[ty + i][tx * 4 + 2] = v.z; t[ty + i][tx * 4 + 3] = v.w;
  }
  __syncthreads();
#pragma unroll
  for (int i = 0; i < 64; i += 16) {
    ushort4 w;
    w.x = t[tx * 4 + 0][ty + i]; w.y = t[tx * 4 + 1][ty + i];
    w.z = t[tx * 4 + 2][ty + i]; w.w = t[tx * 4 + 3][ty + i];
    *reinterpret_cast<ushort4*>(&Vt[(size_t)(bn + ty + i) * 4096 + bk + tx * 4]) = w;
  }
}

__global__ void rowdot_i(const u16* __restrict__ REMA, const float* __restrict__ Wi,
                         const float* __restrict__ bi, float* __restrict__ iv) {
  const int m = blockIdx.x, l = threadIdx.x;
  float s = 0.f;
#pragma unroll
  for (int j = 0; j < 16; ++j) s += b2f(REMA[(size_t)m * 1024 + l + 64 * j]) * Wi[l + 64 * j];
#pragma unroll
  for (int o = 32; o; o >>= 1) s += __shfl_down(s, o);
  if (l == 0) iv[m] = tanhf(s + bi[0]);
}

__global__ void final_kern(const float* __restrict__ REMAp, const float* __restrict__ ZEMAf,
                           const float* __restrict__ iv, const float* __restrict__ Wfin,
                           float* __restrict__ out) {
  const int m = blockIdx.x, l = threadIdx.x;
  const float im = iv[m];
  float s = 0.f;
#pragma unroll
  for (int j = 0; j < 16; ++j) {
    const int n = l + 64 * j;
    const float rp = REMAp[(size_t)m * 1024 + n];
    const float zf = im * tanhf(rp + ZEMAf[(size_t)m * 1024 + n]) + (1.f - im) * rp;
    s += zf * Wfin[n];
  }
#pragma unroll
  for (int o = 32; o; o >>= 1) s += __shfl_down(s, o);
  if (l == 0) out[m] = 1.f / (1.f + expf(-s));
}

extern "C" void kernel_launch(void* const* d_in, const int* in_sizes, int n_in,
                              void* d_out, int out_size, void* d_ws, size_t ws_size,
                              hipStream_t stream) {
  const float* R       = (const float*)d_in[0];
  const float* W_alpha = (const float*)d_in[1];  const float* b_alpha = (const float*)d_in[2];
  const float* W_delta = (const float*)d_in[3];  const float* b_delta = (const float*)d_in[4];
  const float* W_q     = (const float*)d_in[5];  const float* b_q     = (const float*)d_in[6];
  const float* W_k     = (const float*)d_in[7];  const float* b_k     = (const float*)d_in[8];
  const float* W_v     = (const float*)d_in[9];  const float* b_v     = (const float*)d_in[10];
  const float* W_z     = (const float*)d_in[11]; const float* b_z     = (const float*)d_in[12];
  const float* W_f     = (const float*)d_in[13]; const float* b_f     = (const float*)d_in[14];
  const float* W_EMA   = (const float*)d_in[15]; const float* b_EMA   = (const float*)d_in[16];
  const float* W_z_at  = (const float*)d_in[17]; const float* b_z_at  = (const float*)d_in[18];
  const float* W_i     = (const float*)d_in[19]; const float* b_i     = (const float*)d_in[20];
  const float* W_final = (const float*)d_in[21];
  float* out = (float*)d_out;
  uint8_t* w8 = (uint8_t*)d_ws;

  // ---- workspace layout (MB offsets), peak ~110 MB ----
  u16*   Rc     = (u16*)(w8 + 0 * MB);    // [0,16)
  u16*   Wab    = (u16*)(w8 + 16 * MB);   // [16,20)
  u16*   Wdb    = (u16*)(w8 + 20 * MB);   // [20,24)
  u16*   Wqb    = (u16*)(w8 + 24 * MB);
  u16*   Wkb    = (u16*)(w8 + 26 * MB);
  u16*   Wvb    = (u16*)(w8 + 28 * MB);
  u16*   Wzb    = (u16*)(w8 + 30 * MB);
  u16*   Wfb    = (u16*)(w8 + 32 * MB);
  u16*   WEb    = (u16*)(w8 + 34 * MB);
  u16*   Wzab   = (u16*)(w8 + 36 * MB);
  u16*   alphab = (u16*)(w8 + 38 * MB);   // [38,46)
  u16*   deltab = (u16*)(w8 + 46 * MB);   // [46,54)
  u16*   REMAb  = (u16*)(w8 + 54 * MB);   // [54,62) live to end
  u16*   Zb     = (u16*)(w8 + 0 * MB);    // reuse Rc lower
  u16*   Qb     = (u16*)(w8 + 8 * MB);    // reuse Rc upper
  u16*   Kb     = (u16*)(w8 + 38 * MB);   // reuse alpha
  u16*   Vb     = (u16*)(w8 + 46 * MB);   // reuse delta
  u16*   Vtb    = (u16*)(w8 + 0 * MB);    // reuse Z (after QKV)
  u16*   Sb     = (u16*)(w8 + 62 * MB);   // [62,94) scores->P in place
  float* Zat    = (float*)(w8 + 94 * MB); // [94,110)
  float* REMAp  = (float*)(w8 + 62 * MB); // reuse S lower (after attention)
  u16*   REMApb = (u16*)(w8 + 8 * MB);    // reuse Q
  u16*   Zatpb  = (u16*)(w8 + 38 * MB);   // reuse K
  float* ZEMAf  = (float*)(w8 + 78 * MB); // reuse S upper
  float* iv     = (float*)(w8 + 46 * MB); // reuse V (dead)

  const dim3 blk(256);
  // weight conversions
  f2b_kern<<<2048, blk, 0, stream>>>(W_alpha, Wab, 512 * 1024);
  f2b_kern<<<2048, blk, 0, stream>>>(W_delta, Wdb, 512 * 1024);
  f2b_kern<<<1024, blk, 0, stream>>>(W_q, Wqb, 256 * 1024);
  f2b_kern<<<1024, blk, 0, stream>>>(W_k, Wkb, 256 * 1024);
  f2b_kern<<<1024, blk, 0, stream>>>(W_v, Wvb, 256 * 1024);
  f2b_kern<<<1024, blk, 0, stream>>>(W_z, Wzb, 256 * 1024);
  f2b_kern<<<1024, blk, 0, stream>>>(W_f, Wfb, 256 * 1024);
  f2b_kern<<<1024, blk, 0, stream>>>(W_EMA, WEb, 256 * 1024);
  f2b_kern<<<1024, blk, 0, stream>>>(W_z_at, Wzab, 256 * 1024);
  concat_kern<<<8192, blk, 0, stream>>>(R, Rc);

  // alpha / delta (K=2048)
  gemm_bt<EPI_TANH, OUT_B16><<<dim3(8, 32), blk, 0, stream>>>(Rc, Wab, b_alpha, nullptr, nullptr, alphab, 4096, 1024, 2048, 1.f);
  gemm_bt<EPI_TANH, OUT_B16><<<dim3(8, 32), blk, 0, stream>>>(Rc, Wdb, b_delta, nullptr, nullptr, deltab, 4096, 1024, 2048, 1.f);
  ema_combine<<<4096, blk, 0, stream>>>(R, alphab, deltab, REMAb);
  // Z = silu(REMA @ Wz^T + bz)
  gemm_bt<EPI_SILU, OUT_B16><<<dim3(8, 32), blk, 0, stream>>>(REMAb, Wzb, b_z, nullptr, nullptr, Zb, 4096, 1024, 1024, 1.f);
  // Q, K, V
  gemm_bt<EPI_NONE, OUT_B16><<<dim3(8, 32), blk, 0, stream>>>(Zb, Wqb, b_q, nullptr, nullptr, Qb, 4096, 1024, 1024, 1.f);
  gemm_bt<EPI_NONE, OUT_B16><<<dim3(8, 32), blk, 0, stream>>>(Zb, Wkb, b_k, nullptr, nullptr, Kb, 4096, 1024, 1024, 1.f);
  gemm_bt<EPI_NONE, OUT_B16><<<dim3(8, 32), blk, 0, stream>>>(Zb, Wvb, b_v, nullptr, nullptr, Vb, 4096, 1024, 1024, 1.f);
  transpose_b16<<<dim3(16, 64), blk, 0, stream>>>(Vb, Vtb);
  // attention
  gemm_bt<EPI_SCALE, OUT_B16><<<dim3(32, 32), blk, 0, stream>>>(Qb, Kb, nullptr, nullptr, nullptr, Sb, 4096, 4096, 1024, 0.03125f);
  softmax_rows<<<4096, blk, 0, stream>>>(Sb);
  gemm_bt<EPI_NONE, OUT_F32><<<dim3(8, 32), blk, 0, stream>>>(Sb, Vtb, nullptr, nullptr, Zat, nullptr, 4096, 1024, 4096, 1.f);
  // R_EMA_p (fp32 + bf16)
  gemm_bt<EPI_NONE, OUT_DUAL><<<dim3(8, 32), blk, 0, stream>>>(REMAb, WEb, b_EMA, nullptr, REMAp, REMApb, 4096, 1024, 1024, 1.f);
  // Z_at_p = sigmoid(REMAp @ Wf^T + bf) * Z_at
  gemm_bt<EPI_SIGMUL, OUT_B16><<<dim3(8, 32), blk, 0, stream>>>(REMApb, Wfb, b_f, Zat, nullptr, Zatpb, 4096, 1024, 1024, 1.f);
  // Z_EMA_f
  gemm_bt<EPI_NONE, OUT_F32><<<dim3(8, 32), blk, 0, stream>>>(Zatpb, Wzab, b_z_at, nullptr, ZEMAf, nullptr, 4096, 1024, 1024, 1.f);
  // i + final
  rowdot_i<<<4096, 64, 0, stream>>>(REMAb, W_i, b_i, iv);
  final_kern<<<4096, 64, 0, stream>>>(REMAp, ZEMAf, iv, W_final, out);
}

// Round 3
// 370.141 us; speedup vs baseline: 7.0264x; 1.5055x over previous
//
#include <hip/hip_runtime.h>
#include <cstdint>
#include <cmath>

#define MB (1024ull * 1024ull)

typedef unsigned short u16;
typedef __attribute__((ext_vector_type(8))) short short8;
typedef __attribute__((ext_vector_type(4))) float f32x4;

enum { M_TANH = 0, M_ZRE = 1, M_QKV = 2, M_SIG = 3, M_SCALE = 4, M_PVMUL = 5, M_F32 = 6 };

__device__ __forceinline__ u16 f2b(float f) {
  union { float f; uint32_t u; } v; v.f = f;
  uint32_t r = v.u + 0x7FFFu + ((v.u >> 16) & 1u);
  return (u16)(r >> 16);
}
__device__ __forceinline__ float b2f(u16 u) {
  union { uint32_t u; float f; } v; v.u = ((uint32_t)u) << 16;
  return v.f;
}

typedef __attribute__((address_space(3))) uint32_t lds_u32;
typedef const __attribute__((address_space(1))) uint32_t glb_u32;

__device__ __forceinline__ void gload16(const void* g, void* l) {
  __builtin_amdgcn_global_load_lds((glb_u32*)g, (lds_u32*)l, 16, 0, 0);
}

// ---------------- MFMA GEMM: C = epi(A @ B^T + bias) ----------------
// A: 4096xK bf16 (row stride lda), B: NxK bf16 (row stride ldb). N mult of BNT, K mult of 32.
// LDS chunk-XOR swizzle: physical chunk p holds logical chunk p ^ ((row>>1)&3).
template <int MODE, int BNT>
__global__ __launch_bounds__(256) void gemm(const u16* __restrict__ A,
                                            const u16* __restrict__ B,
                                            const float* __restrict__ bias,
                                            const u16* __restrict__ auxb,
                                            u16* __restrict__ Cb,
                                            u16* __restrict__ Cb2,
                                            float* __restrict__ Cf,
                                            int K, int lda, int ldb, float scale) {
  constexpr int NJ = (BNT == 128) ? 4 : 2;
  __shared__ u16 As[128 * 32];
  __shared__ u16 Bs[BNT * 32];
  const int tid = threadIdx.x;
  const int wid = tid >> 6, lane = tid & 63;
  const int bm = blockIdx.y * 128, bn = blockIdx.x * BNT;
  const int wm = wid >> 1, wn = wid & 1;

  // staging: thread t -> row srow, swizzled 8-elem chunk
  const int srow = tid >> 2;
  const int schunk = (tid & 3) ^ ((srow >> 1) & 3);
  const u16* gA = A + (size_t)(bm + srow) * lda + schunk * 8;
  const u16* gB = B + (size_t)(bn + srow) * ldb + schunk * 8;
  u16* ldsA = &As[wid * 512];  // wave-uniform base; HW adds lane*16B
  u16* ldsB = &Bs[wid * 512];

  f32x4 acc[4][NJ];
#pragma unroll
  for (int i = 0; i < 4; ++i)
#pragma unroll
    for (int j = 0; j < NJ; ++j) acc[i][j] = (f32x4){0.f, 0.f, 0.f, 0.f};

  const int ar = lane & 15;
  const int pch = (((lane >> 4) ^ ((ar >> 1) & 3))) * 8;  // swizzled k-chunk

  for (int k0 = 0; k0 < K; k0 += 32) {
    gload16(gA, ldsA);
    gload16(gA + (size_t)64 * lda, ldsA + 2048);
    gload16(gB, ldsB);
    if (BNT == 128) gload16(gB + (size_t)64 * ldb, ldsB + 2048);
    gA += 32; gB += 32;
    __syncthreads();
    short8 af[4], bf[NJ];
#pragma unroll
    for (int i = 0; i < 4; ++i)
      af[i] = *reinterpret_cast<const short8*>(&As[(wm * 64 + i * 16 + ar) * 32 + pch]);
#pragma unroll
    for (int j = 0; j < NJ; ++j)
      bf[j] = *reinterpret_cast<const short8*>(&Bs[(wn * (BNT / 2) + j * 16 + ar) * 32 + pch]);
#pragma unroll
    for (int i = 0; i < 4; ++i)
#pragma unroll
      for (int j = 0; j < NJ; ++j)
        acc[i][j] = __builtin_amdgcn_mfma_f32_16x16x32_bf16(af[i], bf[j], acc[i][j], 0, 0, 0);
    __syncthreads();
  }

#pragma unroll
  for (int i = 0; i < 4; ++i) {
    const int rb = bm + wm * 64 + i * 16 + (lane >> 4) * 4;
#pragma unroll
    for (int j = 0; j < NJ; ++j) {
      const int n = bn + wn * (BNT / 2) + j * 16 + (lane & 15);
#pragma unroll
      for (int r = 0; r < 4; ++r) {
        const int m = rb + r;
        float v = acc[i][j][r];
        if (MODE == M_TANH) {
          v = tanhf(v + bias[n]);
          Cb[(size_t)m * 2048 + n] = f2b(v);
        } else if (MODE == M_ZRE) {
          v += bias[n];
          if (n < 1024) { const float s = v / (1.f + expf(-v)); Cb[(size_t)m * 1024 + n] = f2b(s); }
          else Cb2[(size_t)m * 1024 + (n - 1024)] = f2b(v);
        } else if (MODE == M_QKV) {
          v += bias[n];
          if (n < 2048) Cb[(size_t)m * 2048 + n] = f2b(v);
          else Cb2[(size_t)m * 1024 + (n - 2048)] = f2b(v);
        } else if (MODE == M_SIG) {
          v = 1.f / (1.f + expf(-(v + bias[n])));
          Cb[(size_t)m * 1024 + n] = f2b(v);
        } else if (MODE == M_SCALE) {
          Cb[(size_t)m * 4096 + n] = f2b(v * scale);
        } else if (MODE == M_PVMUL) {
          v *= b2f(auxb[(size_t)m * 1024 + n]);
          Cb[(size_t)m * 1024 + n] = f2b(v);
        } else if (MODE == M_F32) {
          Cf[(size_t)m * 1024 + n] = v + bias[n];
        }
      }
    }
  }
}

// ---------------- helpers ----------------
// all weight f32->bf16 conversions in one launch (11M elems, 2883584 float4s)
__global__ __launch_bounds__(256) void convert_all(
    const float* __restrict__ s0, const float* __restrict__ s1, const float* __restrict__ s2,
    const float* __restrict__ s3, const float* __restrict__ s4, const float* __restrict__ s5,
    const float* __restrict__ s6, const float* __restrict__ s7, const float* __restrict__ s8,
    u16* __restrict__ Wad, u16* __restrict__ Wze, u16* __restrict__ Wqkv,
    u16* __restrict__ Wfb, u16* __restrict__ Wzab) {
  const int idx = blockIdx.x * 256 + threadIdx.x;
  const float* src; u16* dst; int off;
  if      (idx < 524288)  { src = s0; dst = Wad;           off = idx; }
  else if (idx < 1048576) { src = s1; dst = Wad + 2097152; off = idx - 524288; }
  else if (idx < 1310720) { src = s2; dst = Wze;           off = idx - 1048576; }
  else if (idx < 1572864) { src = s3; dst = Wze + 1048576; off = idx - 1310720; }
  else if (idx < 1835008) { src = s4; dst = Wqkv;          off = idx - 1572864; }
  else if (idx < 2097152) { src = s5; dst = Wqkv + 1048576; off = idx - 1835008; }
  else if (idx < 2359296) { src = s6; dst = Wqkv + 2097152; off = idx - 2097152; }
  else if (idx < 2621440) { src = s7; dst = Wfb;           off = idx - 2359296; }
  else                    { src = s8; dst = Wzab;          off = idx - 2621440; }
  const float4 v = reinterpret_cast<const float4*>(src)[off];
  ushort4 o; o.x = f2b(v.x); o.y = f2b(v.y); o.z = f2b(v.z); o.w = f2b(v.w);
  reinterpret_cast<ushort4*>(dst)[off] = o;
}

__global__ void copy_bias(const float* __restrict__ ba, const float* __restrict__ bd,
                          const float* __restrict__ bz, const float* __restrict__ be,
                          const float* __restrict__ bq, const float* __restrict__ bk,
                          const float* __restrict__ bv,
                          float* __restrict__ bad, float* __restrict__ bze,
                          float* __restrict__ bqkv) {
  const int t = threadIdx.x;
  const float4* src; float4* dst;
  switch (blockIdx.x) {
    case 0: src = (const float4*)ba; dst = (float4*)bad; break;
    case 1: src = (const float4*)bd; dst = (float4*)(bad + 1024); break;
    case 2: src = (const float4*)bz; dst = (float4*)bze; break;
    case 3: src = (const float4*)be; dst = (float4*)(bze + 1024); break;
    case 4: src = (const float4*)bq; dst = (float4*)bqkv; break;
    case 5: src = (const float4*)bk; dst = (float4*)(bqkv + 1024); break;
    default: src = (const float4*)bv; dst = (float4*)(bqkv + 2048); break;
  }
  dst[t] = src[t];
}

// Rc[m][k] = k<1024 ? (m>0 ? R[m-1][k] : 0) : R[m][k-1024]   (bf16, [4096][2048])
__global__ __launch_bounds__(256) void concat_kern(const float* __restrict__ R,
                                                   u16* __restrict__ Rc) {
  const int idx = blockIdx.x * 256 + threadIdx.x;
  const int m = idx >> 9;
  const int c = (idx & 511) * 4;
  float4 v;
  if (c < 1024) {
    if (m > 0) v = *reinterpret_cast<const float4*>(&R[(size_t)(m - 1) * 1024 + c]);
    else v = make_float4(0.f, 0.f, 0.f, 0.f);
  } else {
    v = *reinterpret_cast<const float4*>(&R[(size_t)m * 1024 + (c - 1024)]);
  }
  ushort4 o; o.x = f2b(v.x); o.y = f2b(v.y); o.z = f2b(v.z); o.w = f2b(v.w);
  reinterpret_cast<ushort4*>(Rc)[idx] = o;
}

// REMA = alpha*r_t + (1-alpha)*delta*r_prev ; alpha|delta packed in adb [4096][2048]
__global__ __launch_bounds__(256) void ema_combine(const float* __restrict__ R,
                                                   const u16* __restrict__ adb,
                                                   u16* __restrict__ REMA) {
  const int idx = blockIdx.x * 256 + threadIdx.x;  // 1M ushort4 groups
  const int m = idx >> 8, c4 = idx & 255;
  const float4 rt = reinterpret_cast<const float4*>(R)[idx];
  float4 rp = make_float4(0.f, 0.f, 0.f, 0.f);
  if (m > 0) rp = reinterpret_cast<const float4*>(R)[idx - 256];
  const ushort4 a4 = reinterpret_cast<const ushort4*>(adb)[m * 512 + c4];
  const ushort4 d4 = reinterpret_cast<const ushort4*>(adb)[m * 512 + 256 + c4];
  ushort4 o;
  { const float av = b2f(a4.x); o.x = f2b(av * rt.x + (1.f - av) * b2f(d4.x) * rp.x); }
  { const float av = b2f(a4.y); o.y = f2b(av * rt.y + (1.f - av) * b2f(d4.y) * rp.y); }
  { const float av = b2f(a4.z); o.z = f2b(av * rt.z + (1.f - av) * b2f(d4.z) * rp.z); }
  { const float av = b2f(a4.w); o.w = f2b(av * rt.w + (1.f - av) * b2f(d4.w) * rp.w); }
  reinterpret_cast<ushort4*>(REMA)[idx] = o;
}

__device__ __forceinline__ float waveMax(float v) {
#pragma unroll
  for (int o = 32; o; o >>= 1) v = fmaxf(v, __shfl_down(v, o));
  return v;
}
__device__ __forceinline__ float waveSum(float v) {
#pragma unroll
  for (int o = 32; o; o >>= 1) v += __shfl_down(v, o);
  return v;
}

// in-place row softmax on bf16 scores, 4096 cols, one block per row
__global__ __launch_bounds__(256) void softmax_rows(u16* __restrict__ S) {
  u16* p = S + (size_t)blockIdx.x * 4096;
  const int tid = threadIdx.x;
  float v[16];
#pragma unroll
  for (int j = 0; j < 4; ++j) {
    const ushort4 t = *reinterpret_cast<const ushort4*>(&p[tid * 4 + 1024 * j]);
    v[4 * j + 0] = b2f(t.x); v[4 * j + 1] = b2f(t.y);
    v[4 * j + 2] = b2f(t.z); v[4 * j + 3] = b2f(t.w);
  }
  float mx = -INFINITY;
#pragma unroll
  for (int j = 0; j < 16; ++j) mx = fmaxf(mx, v[j]);
  __shared__ float red[4];
  const float wm = waveMax(mx);
  if ((tid & 63) == 0) red[tid >> 6] = wm;
  __syncthreads();
  mx = fmaxf(fmaxf(red[0], red[1]), fmaxf(red[2], red[3]));
  __syncthreads();
  float sum = 0.f;
#pragma unroll
  for (int j = 0; j < 16; ++j) { v[j] = expf(v[j] - mx); sum += v[j]; }
  const float ws_ = waveSum(sum);
  if ((tid & 63) == 0) red[tid >> 6] = ws_;
  __syncthreads();
  const float inv = 1.f / (red[0] + red[1] + red[2] + red[3]);
#pragma unroll
  for (int j = 0; j < 4; ++j) {
    ushort4 t;
    t.x = f2b(v[4 * j + 0] * inv); t.y = f2b(v[4 * j + 1] * inv);
    t.z = f2b(v[4 * j + 2] * inv); t.w = f2b(v[4 * j + 3] * inv);
    *reinterpret_cast<ushort4*>(&p[tid * 4 + 1024 * j]) = t;
  }
}

// Vt[n][k] = V[k][n]; V: [4096][1024] bf16 -> Vt: [1024][4096] bf16
__global__ __launch_bounds__(256) void transpose_b16(const u16* __restrict__ V,
                                                     u16* __restrict__ Vt) {
  __shared__ u16 t[64][72];
  const int bn = blockIdx.x * 64;
  const int bk = blockIdx.y * 64;
  const int tx = threadIdx.x & 15, ty = threadIdx.x >> 4;
#pragma unroll
  for (int i = 0; i < 64; i += 16) {
    const ushort4 v = *reinterpret_cast<const ushort4*>(&V[(size_t)(bk + ty + i) * 1024 + bn + tx * 4]);
    t[ty + i][tx * 4 + 0] = v.x; t[ty + i][tx * 4 + 1] = v.y;
    t[ty + i][tx * 4 + 2] = v.z; t[ty + i][tx * 4 + 3] = v.w;
  }
  __syncthreads();
#pragma unroll
  for (int i = 0; i < 64; i += 16) {
    ushort4 w;
    w.x = t[tx * 4 + 0][ty + i]; w.y = t[tx * 4 + 1][ty + i];
    w.z = t[tx * 4 + 2][ty + i]; w.w = t[tx * 4 + 3][ty + i];
    *reinterpret_cast<ushort4*>(&Vt[(size_t)(bn + ty + i) * 4096 + bk + tx * 4]) = w;
  }
}

__global__ void rowdot_i(const u16* __restrict__ REMA, const float* __restrict__ Wi,
                         const float* __restrict__ bi, float* __restrict__ iv) {
  const int m = blockIdx.x, l = threadIdx.x;
  float s = 0.f;
#pragma unroll
  for (int j = 0; j < 16; ++j) s += b2f(REMA[(size_t)m * 1024 + l + 64 * j]) * Wi[l + 64 * j];
#pragma unroll
  for (int o = 32; o; o >>= 1) s += __shfl_down(s, o);
  if (l == 0) iv[m] = tanhf(s + bi[0]);
}

__global__ void final_kern(const u16* __restrict__ REMApb, const float* __restrict__ ZEMAf,
                           const float* __restrict__ iv, const float* __restrict__ Wfin,
                           float* __restrict__ out) {
  const int m = blockIdx.x, l = threadIdx.x;
  const float im = iv[m];
  float s = 0.f;
#pragma unroll
  for (int j = 0; j < 16; ++j) {
    const int n = l + 64 * j;
    const float rp = b2f(REMApb[(size_t)m * 1024 + n]);
    const float zf = im * tanhf(rp + ZEMAf[(size_t)m * 1024 + n]) + (1.f - im) * rp;
    s += zf * Wfin[n];
  }
#pragma unroll
  for (int o = 32; o; o >>= 1) s += __shfl_down(s, o);
  if (l == 0) out[m] = 1.f / (1.f + expf(-s));
}

extern "C" void kernel_launch(void* const* d_in, const int* in_sizes, int n_in,
                              void* d_out, int out_size, void* d_ws, size_t ws_size,
                              hipStream_t stream) {
  const float* R       = (const float*)d_in[0];
  const float* W_alpha = (const float*)d_in[1];  const float* b_alpha = (const float*)d_in[2];
  const float* W_delta = (const float*)d_in[3];  const float* b_delta = (const float*)d_in[4];
  const float* W_q     = (const float*)d_in[5];  const float* b_q     = (const float*)d_in[6];
  const float* W_k     = (const float*)d_in[7];  const float* b_k     = (const float*)d_in[8];
  const float* W_v     = (const float*)d_in[9];  const float* b_v     = (const float*)d_in[10];
  const float* W_z     = (const float*)d_in[11]; const float* b_z     = (const float*)d_in[12];
  const float* W_f     = (const float*)d_in[13]; const float* b_f     = (const float*)d_in[14];
  const float* W_EMA   = (const float*)d_in[15]; const float* b_EMA   = (const float*)d_in[16];
  const float* W_z_at  = (const float*)d_in[17]; const float* b_z_at  = (const float*)d_in[18];
  const float* W_i     = (const float*)d_in[19]; const float* b_i     = (const float*)d_in[20];
  const float* W_final = (const float*)d_in[21];
  float* out = (float*)d_out;
  uint8_t* w8 = (uint8_t*)d_ws;

  // ---- workspace layout (time-multiplexed), peak ~110 MB ----
  u16*   Rc     = (u16*)(w8 + 0 * MB);     // [0,16)  concat -> adGEMM
  u16*   Zb     = (u16*)(w8 + 0 * MB);     // [0,8)   zremap -> qkv
  u16*   REMApb = (u16*)(w8 + 8 * MB);     // [8,16)  zremap -> final
  u16*   Wad    = (u16*)(w8 + 16 * MB);    // [16,24) conv -> adGEMM
  u16*   fvb    = (u16*)(w8 + 16 * MB);    // [16,24) fgemm -> PV
  u16*   adb    = (u16*)(w8 + 24 * MB);    // [24,40) adGEMM -> ema
  float* ZEMAf  = (float*)(w8 + 24 * MB);  // [24,40) zemaf -> final
  u16*   Wqkv   = (u16*)(w8 + 40 * MB);    // [40,46) conv -> qkv
  u16*   Vtb    = (u16*)(w8 + 40 * MB);    // [40,48) transpose -> PV
  u16*   Wze    = (u16*)(w8 + 46 * MB);    // [46,50) conv -> zremap
  u16*   Wfb    = (u16*)(w8 + 50 * MB);    // [50,52) conv -> fgemm
  u16*   Wzab   = (u16*)(w8 + 52 * MB);    // [52,54) conv -> zemaf
  u16*   REMAb  = (u16*)(w8 + 54 * MB);    // [54,62) ema -> end
  u16*   QKb    = (u16*)(w8 + 62 * MB);    // [62,78) qkv -> scores
  u16*   Zatpb  = (u16*)(w8 + 62 * MB);    // [62,70) PV -> zemaf
  u16*   Vb     = (u16*)(w8 + 78 * MB);    // [78,86) qkv -> transpose
  u16*   Sb     = (u16*)(w8 + 78 * MB);    // [78,110) scores -> PV
  float* iv     = (float*)(w8 + 110 * MB);
  float* bad    = (float*)(w8 + 110 * MB + 64 * 1024);
  float* bze    = bad + 2048;
  float* bqkv   = bze + 2048;

  const dim3 blk(256);
  convert_all<<<11264, blk, 0, stream>>>(W_alpha, W_delta, W_z, W_EMA, W_q, W_k, W_v, W_f, W_z_at,
                                         Wad, Wze, Wqkv, Wfb, Wzab);
  concat_kern<<<8192, blk, 0, stream>>>(R, Rc);
  copy_bias<<<7, blk, 0, stream>>>(b_alpha, b_delta, b_z, b_EMA, b_q, b_k, b_v, bad, bze, bqkv);

  // alpha|delta fused: [4096][2048] = tanh(Rc @ Wad^T + bad)
  gemm<M_TANH, 128><<<dim3(16, 32), blk, 0, stream>>>(Rc, Wad, bad, nullptr, adb, nullptr, nullptr, 2048, 2048, 2048, 1.f);
  ema_combine<<<4096, blk, 0, stream>>>(R, adb, REMAb);
  // Z | REMAp fused: N=2048 (silu -> Zb, plain -> REMApb)
  gemm<M_ZRE, 128><<<dim3(16, 32), blk, 0, stream>>>(REMAb, Wze, bze, nullptr, Zb, REMApb, nullptr, 1024, 1024, 1024, 1.f);
  // QKV fused: N=3072 (QK -> QKb [4096][2048], V -> Vb)
  gemm<M_QKV, 128><<<dim3(24, 32), blk, 0, stream>>>(Zb, Wqkv, bqkv, nullptr, QKb, Vb, nullptr, 1024, 1024, 1024, 1.f);
  // f = sigmoid(REMAp @ Wf^T + bf)  (off the attention critical path)
  gemm<M_SIG, 64><<<dim3(16, 32), blk, 0, stream>>>(REMApb, Wfb, b_f, nullptr, fvb, nullptr, nullptr, 1024, 1024, 1024, 1.f);
  transpose_b16<<<dim3(16, 64), blk, 0, stream>>>(Vb, Vtb);
  // scores
  gemm<M_SCALE, 128><<<dim3(32, 32), blk, 0, stream>>>(QKb, QKb + 1024, nullptr, nullptr, Sb, nullptr, nullptr, 1024, 2048, 2048, 0.03125f);
  softmax_rows<<<4096, blk, 0, stream>>>(Sb);
  // Z_at_p = f * (P @ Vt)
  gemm<M_PVMUL, 64><<<dim3(16, 32), blk, 0, stream>>>(Sb, Vtb, nullptr, fvb, Zatpb, nullptr, nullptr, 4096, 4096, 4096, 1.f);
  // Z_EMA_f (f32)
  gemm<M_F32, 64><<<dim3(16, 32), blk, 0, stream>>>(Zatpb, Wzab, b_z_at, nullptr, nullptr, nullptr, ZEMAf, 1024, 1024, 1024, 1.f);
  // i + final
  rowdot_i<<<4096, 64, 0, stream>>>(REMAb, W_i, b_i, iv);
  final_kern<<<4096, 64, 0, stream>>>(REMApb, ZEMAf, iv, W_final, out);
}

// Round 4
// 345.598 us; speedup vs baseline: 7.5254x; 1.0710x over previous
//
#include <hip/hip_runtime.h>
#include <cstdint>
#include <cmath>

#define MB (1024ull * 1024ull)

typedef unsigned short u16;
typedef __attribute__((ext_vector_type(8))) short short8;
typedef __attribute__((ext_vector_type(4))) float f32x4;

enum { M_TANH = 0, M_ZRE = 1, M_QKV = 2, M_SIG = 3, M_SCALE = 4, M_PVMUL = 5, M_F32 = 6 };

__device__ __forceinline__ u16 f2b(float f) {
  union { float f; uint32_t u; } v; v.f = f;
  uint32_t r = v.u + 0x7FFFu + ((v.u >> 16) & 1u);
  return (u16)(r >> 16);
}
__device__ __forceinline__ float b2f(u16 u) {
  union { uint32_t u; float f; } v; v.u = ((uint32_t)u) << 16;
  return v.f;
}

typedef __attribute__((address_space(3))) uint32_t lds_u32;
typedef const __attribute__((address_space(1))) uint32_t glb_u32;

__device__ __forceinline__ void gload16(const void* g, void* l) {
  __builtin_amdgcn_global_load_lds((glb_u32*)g, (lds_u32*)l, 16, 0, 0);
}

// ---------------- MFMA GEMM: C = epi(A @ B^T + bias) ----------------
// A: 4096xK bf16 (row stride lda), B: NxK bf16 (row stride ldb). K mult of 32.
// Double-buffered LDS (one barrier per K-step, prefetch issued before compute).
// LDS chunk-XOR swizzle: physical chunk p holds logical chunk p ^ ((row>>1)&3).
template <int MODE, int BNT>
__global__ __launch_bounds__(256) void gemm(const u16* __restrict__ A,
                                            const u16* __restrict__ B,
                                            const float* __restrict__ bias,
                                            const u16* __restrict__ auxb,
                                            u16* __restrict__ Cb,
                                            u16* __restrict__ Cb2,
                                            float* __restrict__ Cf,
                                            int K, int lda, int ldb, float scale) {
  constexpr int NJ = (BNT == 128) ? 4 : 2;
  __shared__ u16 As[2][128 * 32];
  __shared__ u16 Bs[2][BNT * 32];
  const int tid = threadIdx.x;
  const int wid = tid >> 6, lane = tid & 63;

  // XCD-aware bijective block swizzle (all grids are multiples of 8 blocks)
  const int gx = gridDim.x, nwg = gx * gridDim.y;
  int id = blockIdx.y * gx + blockIdx.x;
  if ((nwg & 7) == 0) id = (id & 7) * (nwg >> 3) + (id >> 3);
  const int bm = (id / gx) * 128, bn = (id % gx) * BNT;
  const int wm = wid >> 1, wn = wid & 1;

  // staging: thread t -> row srow, swizzled 8-elem chunk
  const int srow = tid >> 2;
  const int schunk = (tid & 3) ^ ((srow >> 1) & 3);
  const u16* gA = A + (size_t)(bm + srow) * lda + schunk * 8;
  const u16* gB = B + (size_t)(bn + srow) * ldb + schunk * 8;

  f32x4 acc[4][NJ];
#pragma unroll
  for (int i = 0; i < 4; ++i)
#pragma unroll
    for (int j = 0; j < NJ; ++j) acc[i][j] = (f32x4){0.f, 0.f, 0.f, 0.f};

  const int ar = lane & 15;
  const int pch = (((lane >> 4) ^ ((ar >> 1) & 3))) * 8;  // swizzled k-chunk

  const int NT = K >> 5;

  auto stage = [&](int buf, int t) {
    const u16* a = gA + (size_t)t * 32;
    const u16* b = gB + (size_t)t * 32;
    gload16(a, &As[buf][wid * 512]);
    gload16(a + (size_t)64 * lda, &As[buf][wid * 512 + 2048]);
    gload16(b, &Bs[buf][wid * 512]);
    if (BNT == 128) gload16(b + (size_t)64 * ldb, &Bs[buf][wid * 512 + 2048]);
  };

  stage(0, 0);
  __syncthreads();
  int cur = 0;
  for (int t = 0; t < NT; ++t) {
    if (t + 1 < NT) stage(cur ^ 1, t + 1);  // prefetch overlaps compute below
    short8 af[4], bf[NJ];
#pragma unroll
    for (int i = 0; i < 4; ++i)
      af[i] = *reinterpret_cast<const short8*>(&As[cur][(wm * 64 + i * 16 + ar) * 32 + pch]);
#pragma unroll
    for (int j = 0; j < NJ; ++j)
      bf[j] = *reinterpret_cast<const short8*>(&Bs[cur][(wn * (BNT / 2) + j * 16 + ar) * 32 + pch]);
#pragma unroll
    for (int i = 0; i < 4; ++i)
#pragma unroll
      for (int j = 0; j < NJ; ++j)
        acc[i][j] = __builtin_amdgcn_mfma_f32_16x16x32_bf16(af[i], bf[j], acc[i][j], 0, 0, 0);
    __syncthreads();  // drains prefetch (vmcnt) + publishes buf cur^1
    cur ^= 1;
  }

#pragma unroll
  for (int i = 0; i < 4; ++i) {
    const int rb = bm + wm * 64 + i * 16 + (lane >> 4) * 4;
#pragma unroll
    for (int j = 0; j < NJ; ++j) {
      const int n = bn + wn * (BNT / 2) + j * 16 + (lane & 15);
#pragma unroll
      for (int r = 0; r < 4; ++r) {
        const int m = rb + r;
        float v = acc[i][j][r];
        if (MODE == M_TANH) {
          v = tanhf(v + bias[n]);
          Cb[(size_t)m * 2048 + n] = f2b(v);
        } else if (MODE == M_ZRE) {
          v += bias[n];
          if (n < 1024) { const float s = v / (1.f + expf(-v)); Cb[(size_t)m * 1024 + n] = f2b(s); }
          else Cb2[(size_t)m * 1024 + (n - 1024)] = f2b(v);
        } else if (MODE == M_QKV) {
          v += bias[n];
          if (n < 2048) Cb[(size_t)m * 2048 + n] = f2b(v);
          else Cb2[(size_t)m * 1024 + (n - 2048)] = f2b(v);
        } else if (MODE == M_SIG) {
          v = 1.f / (1.f + expf(-(v + bias[n])));
          Cb[(size_t)m * 1024 + n] = f2b(v);
        } else if (MODE == M_SCALE) {
          Cb[(size_t)m * 4096 + n] = f2b(v * scale);
        } else if (MODE == M_PVMUL) {
          v *= b2f(auxb[(size_t)m * 1024 + n]);
          Cb[(size_t)m * 1024 + n] = f2b(v);
        } else if (MODE == M_F32) {
          Cf[(size_t)m * 1024 + n] = v + bias[n];
        }
      }
    }
  }
}

// ---------------- helpers ----------------
__global__ __launch_bounds__(256) void convert_all(
    const float* __restrict__ s0, const float* __restrict__ s1, const float* __restrict__ s2,
    const float* __restrict__ s3, const float* __restrict__ s4, const float* __restrict__ s5,
    const float* __restrict__ s6, const float* __restrict__ s7, const float* __restrict__ s8,
    u16* __restrict__ Wad, u16* __restrict__ Wze, u16* __restrict__ Wqkv,
    u16* __restrict__ Wfb, u16* __restrict__ Wzab) {
  const int idx = blockIdx.x * 256 + threadIdx.x;
  const float* src; u16* dst; int off;
  if      (idx < 524288)  { src = s0; dst = Wad;           off = idx; }
  else if (idx < 1048576) { src = s1; dst = Wad + 2097152; off = idx - 524288; }
  else if (idx < 1310720) { src = s2; dst = Wze;           off = idx - 1048576; }
  else if (idx < 1572864) { src = s3; dst = Wze + 1048576; off = idx - 1310720; }
  else if (idx < 1835008) { src = s4; dst = Wqkv;          off = idx - 1572864; }
  else if (idx < 2097152) { src = s5; dst = Wqkv + 1048576; off = idx - 1835008; }
  else if (idx < 2359296) { src = s6; dst = Wqkv + 2097152; off = idx - 2097152; }
  else if (idx < 2621440) { src = s7; dst = Wfb;           off = idx - 2359296; }
  else                    { src = s8; dst = Wzab;          off = idx - 2621440; }
  const float4 v = reinterpret_cast<const float4*>(src)[off];
  ushort4 o; o.x = f2b(v.x); o.y = f2b(v.y); o.z = f2b(v.z); o.w = f2b(v.w);
  reinterpret_cast<ushort4*>(dst)[off] = o;
}

__global__ void copy_bias(const float* __restrict__ ba, const float* __restrict__ bd,
                          const float* __restrict__ bz, const float* __restrict__ be,
                          const float* __restrict__ bq, const float* __restrict__ bk,
                          const float* __restrict__ bv,
                          float* __restrict__ bad, float* __restrict__ bze,
                          float* __restrict__ bqkv) {
  const int t = threadIdx.x;
  const float4* src; float4* dst;
  switch (blockIdx.x) {
    case 0: src = (const float4*)ba; dst = (float4*)bad; break;
    case 1: src = (const float4*)bd; dst = (float4*)(bad + 1024); break;
    case 2: src = (const float4*)bz; dst = (float4*)bze; break;
    case 3: src = (const float4*)be; dst = (float4*)(bze + 1024); break;
    case 4: src = (const float4*)bq; dst = (float4*)bqkv; break;
    case 5: src = (const float4*)bk; dst = (float4*)(bqkv + 1024); break;
    default: src = (const float4*)bv; dst = (float4*)(bqkv + 2048); break;
  }
  dst[t] = src[t];
}

__global__ __launch_bounds__(256) void concat_kern(const float* __restrict__ R,
                                                   u16* __restrict__ Rc) {
  const int idx = blockIdx.x * 256 + threadIdx.x;
  const int m = idx >> 9;
  const int c = (idx & 511) * 4;
  float4 v;
  if (c < 1024) {
    if (m > 0) v = *reinterpret_cast<const float4*>(&R[(size_t)(m - 1) * 1024 + c]);
    else v = make_float4(0.f, 0.f, 0.f, 0.f);
  } else {
    v = *reinterpret_cast<const float4*>(&R[(size_t)m * 1024 + (c - 1024)]);
  }
  ushort4 o; o.x = f2b(v.x); o.y = f2b(v.y); o.z = f2b(v.z); o.w = f2b(v.w);
  reinterpret_cast<ushort4*>(Rc)[idx] = o;
}

__global__ __launch_bounds__(256) void ema_combine(const float* __restrict__ R,
                                                   const u16* __restrict__ adb,
                                                   u16* __restrict__ REMA) {
  const int idx = blockIdx.x * 256 + threadIdx.x;
  const int m = idx >> 8, c4 = idx & 255;
  const float4 rt = reinterpret_cast<const float4*>(R)[idx];
  float4 rp = make_float4(0.f, 0.f, 0.f, 0.f);
  if (m > 0) rp = reinterpret_cast<const float4*>(R)[idx - 256];
  const ushort4 a4 = reinterpret_cast<const ushort4*>(adb)[m * 512 + c4];
  const ushort4 d4 = reinterpret_cast<const ushort4*>(adb)[m * 512 + 256 + c4];
  ushort4 o;
  { const float av = b2f(a4.x); o.x = f2b(av * rt.x + (1.f - av) * b2f(d4.x) * rp.x); }
  { const float av = b2f(a4.y); o.y = f2b(av * rt.y + (1.f - av) * b2f(d4.y) * rp.y); }
  { const float av = b2f(a4.z); o.z = f2b(av * rt.z + (1.f - av) * b2f(d4.z) * rp.z); }
  { const float av = b2f(a4.w); o.w = f2b(av * rt.w + (1.f - av) * b2f(d4.w) * rp.w); }
  reinterpret_cast<ushort4*>(REMA)[idx] = o;
}

__device__ __forceinline__ float waveMax(float v) {
#pragma unroll
  for (int o = 32; o; o >>= 1) v = fmaxf(v, __shfl_down(v, o));
  return v;
}
__device__ __forceinline__ float waveSum(float v) {
#pragma unroll
  for (int o = 32; o; o >>= 1) v += __shfl_down(v, o);
  return v;
}

__global__ __launch_bounds__(256) void softmax_rows(u16* __restrict__ S) {
  u16* p = S + (size_t)blockIdx.x * 4096;
  const int tid = threadIdx.x;
  float v[16];
#pragma unroll
  for (int j = 0; j < 4; ++j) {
    const ushort4 t = *reinterpret_cast<const ushort4*>(&p[tid * 4 + 1024 * j]);
    v[4 * j + 0] = b2f(t.x); v[4 * j + 1] = b2f(t.y);
    v[4 * j + 2] = b2f(t.z); v[4 * j + 3] = b2f(t.w);
  }
  float mx = -INFINITY;
#pragma unroll
  for (int j = 0; j < 16; ++j) mx = fmaxf(mx, v[j]);
  __shared__ float red[4];
  const float wm = waveMax(mx);
  if ((tid & 63) == 0) red[tid >> 6] = wm;
  __syncthreads();
  mx = fmaxf(fmaxf(red[0], red[1]), fmaxf(red[2], red[3]));
  __syncthreads();
  float sum = 0.f;
#pragma unroll
  for (int j = 0; j < 16; ++j) { v[j] = expf(v[j] - mx); sum += v[j]; }
  const float ws_ = waveSum(sum);
  if ((tid & 63) == 0) red[tid >> 6] = ws_;
  __syncthreads();
  const float inv = 1.f / (red[0] + red[1] + red[2] + red[3]);
#pragma unroll
  for (int j = 0; j < 4; ++j) {
    ushort4 t;
    t.x = f2b(v[4 * j + 0] * inv); t.y = f2b(v[4 * j + 1] * inv);
    t.z = f2b(v[4 * j + 2] * inv); t.w = f2b(v[4 * j + 3] * inv);
    *reinterpret_cast<ushort4*>(&p[tid * 4 + 1024 * j]) = t;
  }
}

__global__ __launch_bounds__(256) void transpose_b16(const u16* __restrict__ V,
                                                     u16* __restrict__ Vt) {
  __shared__ u16 t[64][72];
  const int bn = blockIdx.x * 64;
  const int bk = blockIdx.y * 64;
  const int tx = threadIdx.x & 15, ty = threadIdx.x >> 4;
#pragma unroll
  for (int i = 0; i < 64; i += 16) {
    const ushort4 v = *reinterpret_cast<const ushort4*>(&V[(size_t)(bk + ty + i) * 1024 + bn + tx * 4]);
    t[ty + i][tx * 4 + 0] = v.x; t[ty + i][tx * 4 + 1] = v.y;
    t[ty + i][tx * 4 + 2] = v.z; t[ty + i][tx * 4 + 3] = v.w;
  }
  __syncthreads();
#pragma unroll
  for (int i = 0; i < 64; i += 16) {
    ushort4 w;
    w.x = t[tx * 4 + 0][ty + i]; w.y = t[tx * 4 + 1][ty + i];
    w.z = t[tx * 4 + 2][ty + i]; w.w = t[tx * 4 + 3][ty + i];
    *reinterpret_cast<ushort4*>(&Vt[(size_t)(bn + ty + i) * 4096 + bk + tx * 4]) = w;
  }
}

// fused: i = tanh(REMA . Wi + bi); out = sigmoid( (i*tanh(REMAp+ZEMAf)+(1-i)*REMAp) . Wfin )
__global__ void final_kern(const u16* __restrict__ REMAb, const u16* __restrict__ REMApb,
                           const float* __restrict__ ZEMAf,
                           const float* __restrict__ Wi, const float* __restrict__ bi,
                           const float* __restrict__ Wfin, float* __restrict__ out) {
  const int m = blockIdx.x, l = threadIdx.x;
  float si = 0.f;
#pragma unroll
  for (int j = 0; j < 16; ++j) {
    const int n = l + 64 * j;
    si += b2f(REMAb[(size_t)m * 1024 + n]) * Wi[n];
  }
#pragma unroll
  for (int o = 32; o; o >>= 1) si += __shfl_xor(si, o);
  const float im = tanhf(si + bi[0]);
  float s = 0.f;
#pragma unroll
  for (int j = 0; j < 16; ++j) {
    const int n = l + 64 * j;
    const float rp = b2f(REMApb[(size_t)m * 1024 + n]);
    const float zf = im * tanhf(rp + ZEMAf[(size_t)m * 1024 + n]) + (1.f - im) * rp;
    s += zf * Wfin[n];
  }
#pragma unroll
  for (int o = 32; o; o >>= 1) s += __shfl_down(s, o);
  if (l == 0) out[m] = 1.f / (1.f + expf(-s));
}

extern "C" void kernel_launch(void* const* d_in, const int* in_sizes, int n_in,
                              void* d_out, int out_size, void* d_ws, size_t ws_size,
                              hipStream_t stream) {
  const float* R       = (const float*)d_in[0];
  const float* W_alpha = (const float*)d_in[1];  const float* b_alpha = (const float*)d_in[2];
  const float* W_delta = (const float*)d_in[3];  const float* b_delta = (const float*)d_in[4];
  const float* W_q     = (const float*)d_in[5];  const float* b_q     = (const float*)d_in[6];
  const float* W_k     = (const float*)d_in[7];  const float* b_k     = (const float*)d_in[8];
  const float* W_v     = (const float*)d_in[9];  const float* b_v     = (const float*)d_in[10];
  const float* W_z     = (const float*)d_in[11]; const float* b_z     = (const float*)d_in[12];
  const float* W_f     = (const float*)d_in[13]; const float* b_f     = (const float*)d_in[14];
  const float* W_EMA   = (const float*)d_in[15]; const float* b_EMA   = (const float*)d_in[16];
  const float* W_z_at  = (const float*)d_in[17]; const float* b_z_at  = (const float*)d_in[18];
  const float* W_i     = (const float*)d_in[19]; const float* b_i     = (const float*)d_in[20];
  const float* W_final = (const float*)d_in[21];
  float* out = (float*)d_out;
  uint8_t* w8 = (uint8_t*)d_ws;

  // ---- workspace layout (time-multiplexed), peak ~110 MB ----
  u16*   Rc     = (u16*)(w8 + 0 * MB);     // [0,16)  concat -> adGEMM
  u16*   Zb     = (u16*)(w8 + 0 * MB);     // [0,8)   zremap -> qkv
  u16*   REMApb = (u16*)(w8 + 8 * MB);     // [8,16)  zremap -> final
  u16*   Wad    = (u16*)(w8 + 16 * MB);    // [16,24) conv -> adGEMM
  u16*   fvb    = (u16*)(w8 + 16 * MB);    // [16,24) fgemm -> PV
  u16*   adb    = (u16*)(w8 + 24 * MB);    // [24,40) adGEMM -> ema
  float* ZEMAf  = (float*)(w8 + 24 * MB);  // [24,40) zemaf -> final
  u16*   Wqkv   = (u16*)(w8 + 40 * MB);    // [40,46) conv -> qkv
  u16*   Vtb    = (u16*)(w8 + 40 * MB);    // [40,48) transpose -> PV
  u16*   Wze    = (u16*)(w8 + 46 * MB);    // [46,50) conv -> zremap
  u16*   Wfb    = (u16*)(w8 + 50 * MB);    // [50,52) conv -> fgemm
  u16*   Wzab   = (u16*)(w8 + 52 * MB);    // [52,54) conv -> zemaf
  u16*   REMAb  = (u16*)(w8 + 54 * MB);    // [54,62) ema -> end
  u16*   QKb    = (u16*)(w8 + 62 * MB);    // [62,78) qkv -> scores
  u16*   Zatpb  = (u16*)(w8 + 62 * MB);    // [62,70) PV -> zemaf
  u16*   Vb     = (u16*)(w8 + 78 * MB);    // [78,86) qkv -> transpose
  u16*   Sb     = (u16*)(w8 + 78 * MB);    // [78,110) scores -> PV
  float* bad    = (float*)(w8 + 110 * MB + 64 * 1024);
  float* bze    = bad + 2048;
  float* bqkv   = bze + 2048;

  const dim3 blk(256);
  convert_all<<<11264, blk, 0, stream>>>(W_alpha, W_delta, W_z, W_EMA, W_q, W_k, W_v, W_f, W_z_at,
                                         Wad, Wze, Wqkv, Wfb, Wzab);
  concat_kern<<<8192, blk, 0, stream>>>(R, Rc);
  copy_bias<<<7, blk, 0, stream>>>(b_alpha, b_delta, b_z, b_EMA, b_q, b_k, b_v, bad, bze, bqkv);

  // alpha|delta fused: [4096][2048] = tanh(Rc @ Wad^T + bad)
  gemm<M_TANH, 128><<<dim3(16, 32), blk, 0, stream>>>(Rc, Wad, bad, nullptr, adb, nullptr, nullptr, 2048, 2048, 2048, 1.f);
  ema_combine<<<4096, blk, 0, stream>>>(R, adb, REMAb);
  // Z | REMAp fused: N=2048 (silu -> Zb, plain -> REMApb)
  gemm<M_ZRE, 128><<<dim3(16, 32), blk, 0, stream>>>(REMAb, Wze, bze, nullptr, Zb, REMApb, nullptr, 1024, 1024, 1024, 1.f);
  // QKV fused: N=3072 (QK -> QKb [4096][2048], V -> Vb)
  gemm<M_QKV, 128><<<dim3(24, 32), blk, 0, stream>>>(Zb, Wqkv, bqkv, nullptr, QKb, Vb, nullptr, 1024, 1024, 1024, 1.f);
  // f = sigmoid(REMAp @ Wf^T + bf)
  gemm<M_SIG, 64><<<dim3(16, 32), blk, 0, stream>>>(REMApb, Wfb, b_f, nullptr, fvb, nullptr, nullptr, 1024, 1024, 1024, 1.f);
  transpose_b16<<<dim3(16, 64), blk, 0, stream>>>(Vb, Vtb);
  // scores
  gemm<M_SCALE, 128><<<dim3(32, 32), blk, 0, stream>>>(QKb, QKb + 1024, nullptr, nullptr, Sb, nullptr, nullptr, 1024, 2048, 2048, 0.03125f);
  softmax_rows<<<4096, blk, 0, stream>>>(Sb);
  // Z_at_p = f * (P @ Vt)
  gemm<M_PVMUL, 64><<<dim3(16, 32), blk, 0, stream>>>(Sb, Vtb, nullptr, fvb, Zatpb, nullptr, nullptr, 4096, 4096, 4096, 1.f);
  // Z_EMA_f (f32)
  gemm<M_F32, 64><<<dim3(16, 32), blk, 0, stream>>>(Zatpb, Wzab, b_z_at, nullptr, nullptr, nullptr, ZEMAf, 1024, 1024, 1024, 1.f);
  // fused i + final
  final_kern<<<4096, 64, 0, stream>>>(REMAb, REMApb, ZEMAf, W_i, b_i, W_final, out);
}

// Round 6
// 340.662 us; speedup vs baseline: 7.6344x; 1.0145x over previous
//
#include <hip/hip_runtime.h>
#include <cstdint>
#include <cmath>

#define MB (1024ull * 1024ull)

typedef unsigned short u16;
typedef __attribute__((ext_vector_type(8))) short short8;
typedef __attribute__((ext_vector_type(4))) float f32x4;

enum { M_TANH = 0, M_ZRE = 1, M_QKVF = 2, M_SCALE = 3, M_PVRAW = 4, M_F32 = 5 };

__device__ __forceinline__ u16 f2b(float f) {
  union { float f; uint32_t u; } v; v.f = f;
  uint32_t r = v.u + 0x7FFFu + ((v.u >> 16) & 1u);
  return (u16)(r >> 16);
}
__device__ __forceinline__ float b2f(u16 u) {
  union { uint32_t u; float f; } v; v.u = ((uint32_t)u) << 16;
  return v.f;
}

typedef __attribute__((address_space(3))) uint32_t lds_u32;
typedef const __attribute__((address_space(1))) uint32_t glb_u32;

__device__ __forceinline__ void gload16(const void* g, void* l) {
  __builtin_amdgcn_global_load_lds((glb_u32*)g, (lds_u32*)l, 16, 0, 0);
}

// ---------------- MFMA GEMM: C = epi(A @ B^T [+ bias]) ----------------
// Tile BMT x BNT, 4 waves, double-buffered LDS, one barrier per K-step.
// LDS chunk-XOR swizzle: physical chunk p holds logical chunk p ^ ((row>>1)&3).
// M_QKVF: virtual N=4096; blocks with bn>=3072 compute f=sigmoid(A2@B2^T+bias2).
// M_PVRAW: split-K over blockIdx.z; z=0 partial -> Cf, z=1 partial -> (float*)Cb3.
template <int MODE, int BMT, int BNT>
__global__ __launch_bounds__(256) void gemm(const u16* __restrict__ A,
                                            const u16* __restrict__ B,
                                            const float* __restrict__ bias,
                                            const u16* __restrict__ A2,
                                            const u16* __restrict__ B2,
                                            const float* __restrict__ bias2,
                                            u16* __restrict__ Cb,
                                            u16* __restrict__ Cb2,
                                            u16* __restrict__ Cb3,
                                            float* __restrict__ Cf,
                                            int K, int lda, int ldb, float scale) {
  constexpr int WN = (BMT == 64 && BNT == 128) ? 4 : 2;  // waves along N
  constexpr int WM = 4 / WN;
  constexpr int WR = BMT / WM;   // rows per wave
  constexpr int WC = BNT / WN;   // cols per wave
  constexpr int NI = WR / 16;
  constexpr int NJ = WC / 16;
  __shared__ u16 As[2][BMT * 32];
  __shared__ u16 Bs[2][BNT * 32];
  const int tid = threadIdx.x;
  const int wid = tid >> 6, lane = tid & 63;

  // XCD-aware bijective block swizzle (grids per z-slice are multiples of 8)
  const int gx = gridDim.x, nwg = gx * gridDim.y;
  int id = blockIdx.y * gx + blockIdx.x;
  if ((nwg & 7) == 0) id = (id & 7) * (nwg >> 3) + (id >> 3);
  const int bm = (id / gx) * BMT, bn = (id % gx) * BNT;
  const int wm = wid / WN, wn = wid % WN;
  const int rowbase = wm * WR, colbase = wn * WC;

  const bool isf = (MODE == M_QKVF) && (bn >= 3072);
  const u16* Ab = isf ? A2 : A;
  const u16* Bb = isf ? B2 : B;
  const int bnl = isf ? bn - 3072 : bn;
  const int kofs = (MODE == M_PVRAW) ? (int)blockIdx.z * K : 0;

  // staging: thread t -> row srow (64 rows/round), swizzled 8-elem chunk
  const int srow = tid >> 2;
  const int schunk = (tid & 3) ^ ((srow >> 1) & 3);
  const u16* gA = Ab + (size_t)(bm + srow) * lda + kofs + schunk * 8;
  const u16* gB = Bb + (size_t)(bnl + srow) * ldb + kofs + schunk * 8;

  f32x4 acc[NI][NJ];
#pragma unroll
  for (int i = 0; i < NI; ++i)
#pragma unroll
    for (int j = 0; j < NJ; ++j) acc[i][j] = (f32x4){0.f, 0.f, 0.f, 0.f};

  const int ar = lane & 15;
  const int pch = (((lane >> 4) ^ ((ar >> 1) & 3))) * 8;  // swizzled k-chunk

  const int NT = K >> 5;

  auto stage = [&](int buf, int t) {
    const u16* a = gA + (size_t)t * 32;
    const u16* b = gB + (size_t)t * 32;
    gload16(a, &As[buf][wid * 512]);
    if (BMT == 128) gload16(a + (size_t)64 * lda, &As[buf][wid * 512 + 2048]);
    gload16(b, &Bs[buf][wid * 512]);
    if (BNT == 128) gload16(b + (size_t)64 * ldb, &Bs[buf][wid * 512 + 2048]);
  };

  stage(0, 0);
  __syncthreads();
  int cur = 0;
  for (int t = 0; t < NT; ++t) {
    if (t + 1 < NT) stage(cur ^ 1, t + 1);  // prefetch overlaps compute below
    short8 af[NI], bf[NJ];
#pragma unroll
    for (int i = 0; i < NI; ++i)
      af[i] = *reinterpret_cast<const short8*>(&As[cur][(rowbase + i * 16 + ar) * 32 + pch]);
#pragma unroll
    for (int j = 0; j < NJ; ++j)
      bf[j] = *reinterpret_cast<const short8*>(&Bs[cur][(colbase + j * 16 + ar) * 32 + pch]);
#pragma unroll
    for (int i = 0; i < NI; ++i)
#pragma unroll
      for (int j = 0; j < NJ; ++j)
        acc[i][j] = __builtin_amdgcn_mfma_f32_16x16x32_bf16(af[i], bf[j], acc[i][j], 0, 0, 0);
    __syncthreads();  // drains prefetch (vmcnt) + publishes buf cur^1
    cur ^= 1;
  }

  // split-K partial destination: z=0 -> Cf, z=1 -> (float*)Cb3 (disjoint ws regions)
  float* Cfz = Cf;
  if (MODE == M_PVRAW && blockIdx.z != 0) Cfz = (float*)Cb3;

#pragma unroll
  for (int i = 0; i < NI; ++i) {
    const int rb = bm + rowbase + i * 16 + (lane >> 4) * 4;
#pragma unroll
    for (int j = 0; j < NJ; ++j) {
      const int n = bn + colbase + j * 16 + (lane & 15);
#pragma unroll
      for (int r = 0; r < 4; ++r) {
        const int m = rb + r;
        float v = acc[i][j][r];
        if (MODE == M_TANH) {
          v = tanhf(v + bias[n]);
          Cb[(size_t)m * 2048 + n] = f2b(v);
        } else if (MODE == M_ZRE) {
          v += bias[n];
          if (n < 1024) { const float s = v / (1.f + expf(-v)); Cb[(size_t)m * 1024 + n] = f2b(s); }
          else Cb2[(size_t)m * 1024 + (n - 1024)] = f2b(v);
        } else if (MODE == M_QKVF) {
          if (isf) {
            const int nl = n - 3072;
            const float s = 1.f / (1.f + expf(-(v + bias2[nl])));
            Cb3[(size_t)m * 1024 + nl] = f2b(s);
          } else {
            v += bias[n];
            if (n < 2048) Cb[(size_t)m * 2048 + n] = f2b(v);
            else Cb2[(size_t)m * 1024 + (n - 2048)] = f2b(v);
          }
        } else if (MODE == M_SCALE) {
          Cb[(size_t)m * 4096 + n] = f2b(v * scale);
        } else if (MODE == M_PVRAW) {
          Cfz[(size_t)m * 1024 + n] = v;
        } else if (MODE == M_F32) {
          Cf[(size_t)m * 1024 + n] = v + bias[n];
        }
      }
    }
  }
}

// Zatp = f2b( (p0 + p1) * f )
__global__ __launch_bounds__(256) void pv_reduce(const float* __restrict__ p0,
                                                 const float* __restrict__ p1,
                                                 const u16* __restrict__ fvb,
                                                 u16* __restrict__ Zatp) {
  const int idx = blockIdx.x * 256 + threadIdx.x;  // 1M float4 groups
  const float4 a = reinterpret_cast<const float4*>(p0)[idx];
  const float4 b = reinterpret_cast<const float4*>(p1)[idx];
  const ushort4 f4 = reinterpret_cast<const ushort4*>(fvb)[idx];
  ushort4 o;
  o.x = f2b((a.x + b.x) * b2f(f4.x));
  o.y = f2b((a.y + b.y) * b2f(f4.y));
  o.z = f2b((a.z + b.z) * b2f(f4.z));
  o.w = f2b((a.w + b.w) * b2f(f4.w));
  reinterpret_cast<ushort4*>(Zatp)[idx] = o;
}

// ---------------- helpers ----------------
__global__ __launch_bounds__(256) void convert_all(
    const float* __restrict__ s0, const float* __restrict__ s1, const float* __restrict__ s2,
    const float* __restrict__ s3, const float* __restrict__ s4, const float* __restrict__ s5,
    const float* __restrict__ s6, const float* __restrict__ s7, const float* __restrict__ s8,
    u16* __restrict__ Wad, u16* __restrict__ Wze, u16* __restrict__ Wqkv,
    u16* __restrict__ Wfb, u16* __restrict__ Wzab) {
  const int idx = blockIdx.x * 256 + threadIdx.x;
  const float* src; u16* dst; int off;
  if      (idx < 524288)  { src = s0; dst = Wad;           off = idx; }
  else if (idx < 1048576) { src = s1; dst = Wad + 2097152; off = idx - 524288; }
  else if (idx < 1310720) { src = s2; dst = Wze;           off = idx - 1048576; }
  else if (idx < 1572864) { src = s3; dst = Wze + 1048576; off = idx - 1310720; }
  else if (idx < 1835008) { src = s4; dst = Wqkv;          off = idx - 1572864; }
  else if (idx < 2097152) { src = s5; dst = Wqkv + 1048576; off = idx - 1835008; }
  else if (idx < 2359296) { src = s6; dst = Wqkv + 2097152; off = idx - 2097152; }
  else if (idx < 2621440) { src = s7; dst = Wfb;           off = idx - 2359296; }
  else                    { src = s8; dst = Wzab;          off = idx - 2621440; }
  const float4 v = reinterpret_cast<const float4*>(src)[off];
  ushort4 o; o.x = f2b(v.x); o.y = f2b(v.y); o.z = f2b(v.z); o.w = f2b(v.w);
  reinterpret_cast<ushort4*>(dst)[off] = o;
}

__global__ void copy_bias(const float* __restrict__ ba, const float* __restrict__ bd,
                          const float* __restrict__ bz, const float* __restrict__ be,
                          const float* __restrict__ bq, const float* __restrict__ bk,
                          const float* __restrict__ bv,
                          float* __restrict__ bad, float* __restrict__ bze,
                          float* __restrict__ bqkv) {
  const int t = threadIdx.x;
  const float4* src; float4* dst;
  switch (blockIdx.x) {
    case 0: src = (const float4*)ba; dst = (float4*)bad; break;
    case 1: src = (const float4*)bd; dst = (float4*)(bad + 1024); break;
    case 2: src = (const float4*)bz; dst = (float4*)bze; break;
    case 3: src = (const float4*)be; dst = (float4*)(bze + 1024); break;
    case 4: src = (const float4*)bq; dst = (float4*)bqkv; break;
    case 5: src = (const float4*)bk; dst = (float4*)(bqkv + 1024); break;
    default: src = (const float4*)bv; dst = (float4*)(bqkv + 2048); break;
  }
  dst[t] = src[t];
}

__global__ __launch_bounds__(256) void concat_kern(const float* __restrict__ R,
                                                   u16* __restrict__ Rc) {
  const int idx = blockIdx.x * 256 + threadIdx.x;
  const int m = idx >> 9;
  const int c = (idx & 511) * 4;
  float4 v;
  if (c < 1024) {
    if (m > 0) v = *reinterpret_cast<const float4*>(&R[(size_t)(m - 1) * 1024 + c]);
    else v = make_float4(0.f, 0.f, 0.f, 0.f);
  } else {
    v = *reinterpret_cast<const float4*>(&R[(size_t)m * 1024 + (c - 1024)]);
  }
  ushort4 o; o.x = f2b(v.x); o.y = f2b(v.y); o.z = f2b(v.z); o.w = f2b(v.w);
  reinterpret_cast<ushort4*>(Rc)[idx] = o;
}

__global__ __launch_bounds__(256) void ema_combine(const float* __restrict__ R,
                                                   const u16* __restrict__ adb,
                                                   u16* __restrict__ REMA) {
  const int idx = blockIdx.x * 256 + threadIdx.x;
  const int m = idx >> 8, c4 = idx & 255;
  const float4 rt = reinterpret_cast<const float4*>(R)[idx];
  float4 rp = make_float4(0.f, 0.f, 0.f, 0.f);
  if (m > 0) rp = reinterpret_cast<const float4*>(R)[idx - 256];
  const ushort4 a4 = reinterpret_cast<const ushort4*>(adb)[m * 512 + c4];
  const ushort4 d4 = reinterpret_cast<const ushort4*>(adb)[m * 512 + 256 + c4];
  ushort4 o;
  { const float av = b2f(a4.x); o.x = f2b(av * rt.x + (1.f - av) * b2f(d4.x) * rp.x); }
  { const float av = b2f(a4.y); o.y = f2b(av * rt.y + (1.f - av) * b2f(d4.y) * rp.y); }
  { const float av = b2f(a4.z); o.z = f2b(av * rt.z + (1.f - av) * b2f(d4.z) * rp.z); }
  { const float av = b2f(a4.w); o.w = f2b(av * rt.w + (1.f - av) * b2f(d4.w) * rp.w); }
  reinterpret_cast<ushort4*>(REMA)[idx] = o;
}

__device__ __forceinline__ float waveMax(float v) {
#pragma unroll
  for (int o = 32; o; o >>= 1) v = fmaxf(v, __shfl_down(v, o));
  return v;
}
__device__ __forceinline__ float waveSum(float v) {
#pragma unroll
  for (int o = 32; o; o >>= 1) v += __shfl_down(v, o);
  return v;
}

__global__ __launch_bounds__(256) void softmax_rows(u16* __restrict__ S) {
  u16* p = S + (size_t)blockIdx.x * 4096;
  const int tid = threadIdx.x;
  float v[16];
#pragma unroll
  for (int j = 0; j < 4; ++j) {
    const ushort4 t = *reinterpret_cast<const ushort4*>(&p[tid * 4 + 1024 * j]);
    v[4 * j + 0] = b2f(t.x); v[4 * j + 1] = b2f(t.y);
    v[4 * j + 2] = b2f(t.z); v[4 * j + 3] = b2f(t.w);
  }
  float mx = -INFINITY;
#pragma unroll
  for (int j = 0; j < 16; ++j) mx = fmaxf(mx, v[j]);
  __shared__ float red[4];
  const float wm = waveMax(mx);
  if ((tid & 63) == 0) red[tid >> 6] = wm;
  __syncthreads();
  mx = fmaxf(fmaxf(red[0], red[1]), fmaxf(red[2], red[3]));
  __syncthreads();
  float sum = 0.f;
#pragma unroll
  for (int j = 0; j < 16; ++j) { v[j] = expf(v[j] - mx); sum += v[j]; }
  const float ws_ = waveSum(sum);
  if ((tid & 63) == 0) red[tid >> 6] = ws_;
  __syncthreads();
  const float inv = 1.f / (red[0] + red[1] + red[2] + red[3]);
#pragma unroll
  for (int j = 0; j < 4; ++j) {
    ushort4 t;
    t.x = f2b(v[4 * j + 0] * inv); t.y = f2b(v[4 * j + 1] * inv);
    t.z = f2b(v[4 * j + 2] * inv); t.w = f2b(v[4 * j + 3] * inv);
    *reinterpret_cast<ushort4*>(&p[tid * 4 + 1024 * j]) = t;
  }
}

__global__ __launch_bounds__(256) void transpose_b16(const u16* __restrict__ V,
                                                     u16* __restrict__ Vt) {
  __shared__ u16 t[64][72];
  const int bn = blockIdx.x * 64;
  const int bk = blockIdx.y * 64;
  const int tx = threadIdx.x & 15, ty = threadIdx.x >> 4;
#pragma unroll
  for (int i = 0; i < 64; i += 16) {
    const ushort4 v = *reinterpret_cast<const ushort4*>(&V[(size_t)(bk + ty + i) * 1024 + bn + tx * 4]);
    t[ty + i][tx * 4 + 0] = v.x; t[ty + i][tx * 4 + 1] = v.y;
    t[ty + i][tx * 4 + 2] = v.z; t[ty + i][tx * 4 + 3] = v.w;
  }
  __syncthreads();
#pragma unroll
  for (int i = 0; i < 64; i += 16) {
    ushort4 w;
    w.x = t[tx * 4 + 0][ty + i]; w.y = t[tx * 4 + 1][ty + i];
    w.z = t[tx * 4 + 2][ty + i]; w.w = t[tx * 4 + 3][ty + i];
    *reinterpret_cast<ushort4*>(&Vt[(size_t)(bn + ty + i) * 4096 + bk + tx * 4]) = w;
  }
}

// fused: i = tanh(REMA . Wi + bi); out = sigmoid( (i*tanh(REMAp+ZEMAf)+(1-i)*REMAp) . Wfin )
__global__ void final_kern(const u16* __restrict__ REMAb, const u16* __restrict__ REMApb,
                           const float* __restrict__ ZEMAf,
                           const float* __restrict__ Wi, const float* __restrict__ bi,
                           const float* __restrict__ Wfin, float* __restrict__ out) {
  const int m = blockIdx.x, l = threadIdx.x;
  float si = 0.f;
#pragma unroll
  for (int j = 0; j < 16; ++j) {
    const int n = l + 64 * j;
    si += b2f(REMAb[(size_t)m * 1024 + n]) * Wi[n];
  }
#pragma unroll
  for (int o = 32; o; o >>= 1) si += __shfl_xor(si, o);
  const float im = tanhf(si + bi[0]);
  float s = 0.f;
#pragma unroll
  for (int j = 0; j < 16; ++j) {
    const int n = l + 64 * j;
    const float rp = b2f(REMApb[(size_t)m * 1024 + n]);
    const float zf = im * tanhf(rp + ZEMAf[(size_t)m * 1024 + n]) + (1.f - im) * rp;
    s += zf * Wfin[n];
  }
#pragma unroll
  for (int o = 32; o; o >>= 1) s += __shfl_down(s, o);
  if (l == 0) out[m] = 1.f / (1.f + expf(-s));
}

extern "C" void kernel_launch(void* const* d_in, const int* in_sizes, int n_in,
                              void* d_out, int out_size, void* d_ws, size_t ws_size,
                              hipStream_t stream) {
  const float* R       = (const float*)d_in[0];
  const float* W_alpha = (const float*)d_in[1];  const float* b_alpha = (const float*)d_in[2];
  const float* W_delta = (const float*)d_in[3];  const float* b_delta = (const float*)d_in[4];
  const float* W_q     = (const float*)d_in[5];  const float* b_q     = (const float*)d_in[6];
  const float* W_k     = (const float*)d_in[7];  const float* b_k     = (const float*)d_in[8];
  const float* W_v     = (const float*)d_in[9];  const float* b_v     = (const float*)d_in[10];
  const float* W_z     = (const float*)d_in[11]; const float* b_z     = (const float*)d_in[12];
  const float* W_f     = (const float*)d_in[13]; const float* b_f     = (const float*)d_in[14];
  const float* W_EMA   = (const float*)d_in[15]; const float* b_EMA   = (const float*)d_in[16];
  const float* W_z_at  = (const float*)d_in[17]; const float* b_z_at  = (const float*)d_in[18];
  const float* W_i     = (const float*)d_in[19]; const float* b_i     = (const float*)d_in[20];
  const float* W_final = (const float*)d_in[21];
  float* out = (float*)d_out;
  uint8_t* w8 = (uint8_t*)d_ws;

  // ---- workspace layout (time-multiplexed), peak ~110 MB ----
  u16*   Rc     = (u16*)(w8 + 0 * MB);     // [0,16)  concat -> adGEMM
  u16*   Zb     = (u16*)(w8 + 0 * MB);     // [0,8)   zre -> qkvf
  u16*   Zatpb  = (u16*)(w8 + 0 * MB);     // [0,8)   pv_reduce -> zemaf
  u16*   REMApb = (u16*)(w8 + 8 * MB);     // [8,16)  zre -> final
  u16*   Wad    = (u16*)(w8 + 16 * MB);    // [16,24) conv -> adGEMM
  u16*   fvb    = (u16*)(w8 + 16 * MB);    // [16,24) qkvf -> pv_reduce
  u16*   adb    = (u16*)(w8 + 24 * MB);    // [24,40) adGEMM -> ema
  float* pvp0   = (float*)(w8 + 24 * MB);  // [24,40) PV partial 0 (adb dead)
  float* ZEMAf  = (float*)(w8 + 24 * MB);  // [24,40) zemaf -> final
  u16*   Wqkv   = (u16*)(w8 + 40 * MB);    // [40,46) conv -> qkvf
  u16*   Vtb    = (u16*)(w8 + 40 * MB);    // [40,48) transpose -> PV
  u16*   Wze    = (u16*)(w8 + 46 * MB);    // [46,50) conv -> zre
  u16*   Wfb    = (u16*)(w8 + 50 * MB);    // [50,52) conv -> qkvf(f)
  u16*   Wzab   = (u16*)(w8 + 52 * MB);    // [52,54) conv -> zemaf
  u16*   REMAb  = (u16*)(w8 + 54 * MB);    // [54,62) ema -> end
  u16*   QKb    = (u16*)(w8 + 62 * MB);    // [62,78) qkvf -> scores
  float* pvp1   = (float*)(w8 + 62 * MB);  // [62,78) PV partial 1 (QKb dead)
  u16*   Vb     = (u16*)(w8 + 78 * MB);    // [78,86) qkvf -> transpose
  u16*   Sb     = (u16*)(w8 + 78 * MB);    // [78,110) scores -> PV
  float* bad    = (float*)(w8 + 110 * MB + 64 * 1024);
  float* bze    = bad + 2048;
  float* bqkv   = bze + 2048;

  const dim3 blk(256);
  convert_all<<<11264, blk, 0, stream>>>(W_alpha, W_delta, W_z, W_EMA, W_q, W_k, W_v, W_f, W_z_at,
                                         Wad, Wze, Wqkv, Wfb, Wzab);
  concat_kern<<<8192, blk, 0, stream>>>(R, Rc);
  copy_bias<<<7, blk, 0, stream>>>(b_alpha, b_delta, b_z, b_EMA, b_q, b_k, b_v, bad, bze, bqkv);

  // alpha|delta fused: [4096][2048] = tanh(Rc @ Wad^T + bad)   (1024 blocks)
  gemm<M_TANH, 64, 128><<<dim3(16, 64), blk, 0, stream>>>(
      Rc, Wad, bad, nullptr, nullptr, nullptr, adb, nullptr, nullptr, nullptr, 2048, 2048, 2048, 1.f);
  ema_combine<<<4096, blk, 0, stream>>>(R, adb, REMAb);
  // Z | REMAp fused: N=2048 (silu -> Zb, plain -> REMApb)   (1024 blocks)
  gemm<M_ZRE, 64, 128><<<dim3(16, 64), blk, 0, stream>>>(
      REMAb, Wze, bze, nullptr, nullptr, nullptr, Zb, REMApb, nullptr, nullptr, 1024, 1024, 1024, 1.f);
  // QKV + f merged: virtual N=4096 (QK->QKb, V->Vb, f->fvb)   (2048 blocks)
  gemm<M_QKVF, 64, 128><<<dim3(32, 64), blk, 0, stream>>>(
      Zb, Wqkv, bqkv, REMApb, Wfb, b_f, QKb, Vb, fvb, nullptr, 1024, 1024, 1024, 1.f);
  transpose_b16<<<dim3(16, 64), blk, 0, stream>>>(Vb, Vtb);
  // scores (1024 blocks, 128x128)
  gemm<M_SCALE, 128, 128><<<dim3(32, 32), blk, 0, stream>>>(
      QKb, QKb + 1024, nullptr, nullptr, nullptr, nullptr, Sb, nullptr, nullptr, nullptr, 1024, 2048, 2048, 0.03125f);
  softmax_rows<<<4096, blk, 0, stream>>>(Sb);
  // PV split-K=2 raw partials: z=0 -> pvp0, z=1 -> pvp1 (via Cb3)
  gemm<M_PVRAW, 128, 64><<<dim3(16, 32, 2), blk, 0, stream>>>(
      Sb, Vtb, nullptr, nullptr, nullptr, nullptr, nullptr, nullptr, (u16*)pvp1, pvp0, 2048, 4096, 4096, 1.f);
  // Zatp = f * (p0 + p1)
  pv_reduce<<<4096, blk, 0, stream>>>(pvp0, pvp1, fvb, Zatpb);
  // Z_EMA_f (f32)   (512 blocks)
  gemm<M_F32, 64, 128><<<dim3(8, 64), blk, 0, stream>>>(
      Zatpb, Wzab, b_z_at, nullptr, nullptr, nullptr, nullptr, nullptr, nullptr, ZEMAf, 1024, 1024, 1024, 1.f);
  // fused i + final
  final_kern<<<4096, 64, 0, stream>>>(REMAb, REMApb, ZEMAf, W_i, b_i, W_final, out);
}